// Round 5
// baseline (274.140 us; speedup 1.0000x reference)
//
#include <hip/hip_runtime.h>

#define NEG_SLOPE 0.2f

typedef _Float16 f16x8 __attribute__((ext_vector_type(8)));
typedef float f32x4 __attribute__((ext_vector_type(4)));

__device__ __forceinline__ float lrelu(float x){ return x >= 0.0f ? x : NEG_SLOPE * x; }
__device__ __forceinline__ float elu1(float x){ return x > 0.0f ? x : __expf(x) - 1.0f; }

__device__ __forceinline__ void gload_lds16(const _Float16* g, _Float16* l){
  __builtin_amdgcn_global_load_lds(
      (const __attribute__((address_space(1))) unsigned int*)g,
      (__attribute__((address_space(3))) unsigned int*)l, 16, 0, 0);
}

__device__ __forceinline__ f16x8 splat8(_Float16 x){
  f16x8 v;
  #pragma unroll
  for (int j = 0; j < 8; ++j) v[j] = x;
  return v;
}

union H8U { uint4 u; _Float16 h[8]; };

// ---------------- fused prep: convert x -> fp16, transpose W1/W2 -> fp16, count degrees ----------------
__global__ __launch_bounds__(256) void prep_kernel(
    const float* __restrict__ x, _Float16* __restrict__ x16, int cvtb, int valid, int total,
    const float* __restrict__ W1, _Float16* __restrict__ W1T,
    const float* __restrict__ W2, _Float16* __restrict__ W2T,
    const int* __restrict__ dstp, int E, int N, int* __restrict__ counts)
{
  __shared__ float tile[32][33];
  int b = blockIdx.x;
  const int tid = threadIdx.x;
  if (b < cvtb){
    int i = (b * 256 + tid) * 8;
    if (i < total){
      H8U o;
      if (i + 8 <= valid){
        float4 v0 = *(const float4*)(x + i);
        float4 v1 = *(const float4*)(x + i + 4);
        o.h[0] = (_Float16)v0.x; o.h[1] = (_Float16)v0.y; o.h[2] = (_Float16)v0.z; o.h[3] = (_Float16)v0.w;
        o.h[4] = (_Float16)v1.x; o.h[5] = (_Float16)v1.y; o.h[6] = (_Float16)v1.z; o.h[7] = (_Float16)v1.w;
      } else {
        #pragma unroll
        for (int j = 0; j < 8; ++j) o.h[j] = (i + j < valid) ? (_Float16)x[i + j] : (_Float16)0.0f;
      }
      *(uint4*)(x16 + i) = o.u;
    }
    return;
  }
  b -= cvtb;
  if (b < 128 + 256){
    const float* W; _Float16* WT; int K, Nn, bb;
    if (b < 128){ W = W1; WT = W1T; K = 256; Nn = 512; bb = b; }
    else        { W = W2; WT = W2T; K = 512; Nn = 512; bb = b - 128; }
    const int nbk = K / 32;
    const int k0 = (bb % nbk) * 32, n0 = (bb / nbk) * 32;
    const int tx = tid & 31, ty = tid >> 5;
    for (int i = ty; i < 32; i += 8)
      tile[i][tx] = W[(size_t)(k0 + i) * Nn + n0 + tx];
    __syncthreads();
    for (int i = ty; i < 32; i += 8)
      WT[(size_t)(n0 + i) * K + k0 + tx] = (_Float16)tile[tx][i];
    return;
  }
  b -= 384;
  {
    int i = b * 256 + tid;
    if (i < E + N){
      int d = (i < E) ? dstp[i] : (i - E);
      atomicAdd(&counts[d], 1);
    }
  }
}

// ---------------- CSR scan / fill ----------------
__global__ __launch_bounds__(256) void block_sum_kernel(const int* __restrict__ counts, int N, int* __restrict__ bsum){
  __shared__ int ws[4];
  const int lane = threadIdx.x & 63, wave = threadIdx.x >> 6;
  int i = blockIdx.x * 256 + threadIdx.x;
  int v = (i < N) ? counts[i] : 0;
  #pragma unroll
  for (int msk = 1; msk < 64; msk <<= 1) v += __shfl_xor(v, msk);
  if (lane == 0) ws[wave] = v;
  __syncthreads();
  if (threadIdx.x == 0) bsum[blockIdx.x] = ws[0] + ws[1] + ws[2] + ws[3];
}

__global__ __launch_bounds__(256) void scan_bsum_kernel(int* __restrict__ bsum, int nb, int* __restrict__ offsets, int N){
  __shared__ int tmp[256];
  const int t = threadIdx.x;
  int v = (t < nb) ? bsum[t] : 0;
  tmp[t] = v;
  __syncthreads();
  #pragma unroll
  for (int ofs = 1; ofs < 256; ofs <<= 1){
    int add = (t >= ofs) ? tmp[t - ofs] : 0;
    __syncthreads();
    tmp[t] += add;
    __syncthreads();
  }
  if (t < nb) bsum[t] = tmp[t] - v;          // exclusive
  if (t == nb - 1) offsets[N] = tmp[t];      // total
}

__global__ __launch_bounds__(256) void scan_within_kernel(const int* __restrict__ counts, const int* __restrict__ bsum,
                                                          int* __restrict__ offsets, int N){
  __shared__ int wsum[4];
  const int lane = threadIdx.x & 63, wave = threadIdx.x >> 6;
  int i = blockIdx.x * 256 + threadIdx.x;
  int v = (i < N) ? counts[i] : 0;
  int sc = v;
  #pragma unroll
  for (int ofs = 1; ofs < 64; ofs <<= 1){
    int t = __shfl_up(sc, ofs);
    if (lane >= ofs) sc += t;
  }
  if (lane == 63) wsum[wave] = sc;
  __syncthreads();
  int woff = 0;
  #pragma unroll
  for (int w = 0; w < 4; ++w) if (w < wave) woff += wsum[w];
  if (i < N) offsets[i] = bsum[blockIdx.x] + woff + sc - v;
}

__global__ void fill_kernel(const int* __restrict__ src, const int* __restrict__ dst, int E, int N,
                            const int* __restrict__ offsets, int* __restrict__ cursor, int* __restrict__ csr_src){
  int i = blockIdx.x * blockDim.x + threadIdx.x;
  if (i < E + N){
    int s, d;
    if (i < E){ s = src[i]; d = dst[i]; } else { s = i - E; d = i - E; }
    int pos = atomicAdd(&cursor[d], 1);
    csr_src[offsets[d] + pos] = s;
  }
}

// ---------------- fp16 MFMA GEMM + fused alpha epilogue ----------------
__global__ __launch_bounds__(256) void gemm_f16_mfma(
    const _Float16* __restrict__ A, const _Float16* __restrict__ BT,
    _Float16* __restrict__ C,
    const float* __restrict__ a_src, const float* __restrict__ a_dst,
    float* __restrict__ AS, float* __restrict__ AD,
    int M, int Nn, int K)
{
  __shared__ _Float16 As[128 * 64];
  __shared__ _Float16 Bs[128 * 64];
  const int tid = threadIdx.x;
  const int lane = tid & 63;
  const int wave = tid >> 6;
  const int wr = wave >> 1, wc = wave & 1;
  const int row0 = blockIdx.x * 128;
  const int col0 = blockIdx.y * 128;
  const int r15 = lane & 15;
  const int kgrp = lane >> 4;

  f32x4 acc[4][4];
  #pragma unroll
  for (int m = 0; m < 4; ++m)
    #pragma unroll
    for (int n = 0; n < 4; ++n)
      acc[m][n] = (f32x4){0.f, 0.f, 0.f, 0.f};

  for (int k0 = 0; k0 < K; k0 += 64){
    #pragma unroll
    for (int it = 0; it < 4; ++it){
      int idx = it * 2048 + tid * 8;
      int r = idx >> 6, c = idx & 63;
      gload_lds16(A  + (size_t)(row0 + r) * K + k0 + c, &As[idx]);
      gload_lds16(BT + (size_t)(col0 + r) * K + k0 + c, &Bs[idx]);
    }
    __syncthreads();
    #pragma unroll
    for (int kk = 0; kk < 2; ++kk){
      const int cc = kk * 32 + kgrp * 8;
      f16x8 av[4], bv[4];
      #pragma unroll
      for (int q = 0; q < 4; ++q){
        av[q] = *(const f16x8*)&As[(wr * 64 + q * 16 + r15) * 64 + cc];
        bv[q] = *(const f16x8*)&Bs[(wc * 64 + q * 16 + r15) * 64 + cc];
      }
      #pragma unroll
      for (int m = 0; m < 4; ++m)
        #pragma unroll
        for (int n = 0; n < 4; ++n)
          acc[m][n] = __builtin_amdgcn_mfma_f32_16x16x32_f16(av[m], bv[n], acc[m][n], 0, 0, 0);
    }
    __syncthreads();
  }
  #pragma unroll
  for (int m = 0; m < 4; ++m){
    #pragma unroll
    for (int n = 0; n < 4; ++n){
      int col = col0 + wc * 64 + n * 16 + r15;
      #pragma unroll
      for (int j = 0; j < 4; ++j){
        int row = row0 + wr * 64 + m * 16 + kgrp * 4 + j;
        if (row < M) C[(size_t)row * Nn + col] = (_Float16)acc[m][n][j];
      }
    }
  }
  // fused alpha epilogue: wave owns head = 2*by + wc over its 64 rows
  const int head = 2 * blockIdx.y + wc;
  float asv[4], adv[4];
  #pragma unroll
  for (int n = 0; n < 4; ++n){
    asv[n] = a_src[head * 64 + n * 16 + r15];
    adv[n] = a_dst[head * 64 + n * 16 + r15];
  }
  #pragma unroll
  for (int m = 0; m < 4; ++m){
    #pragma unroll
    for (int j = 0; j < 4; ++j){
      float ps = 0.f, pd = 0.f;
      #pragma unroll
      for (int n = 0; n < 4; ++n){
        float c = acc[m][n][j];
        ps += c * asv[n];
        pd += c * adv[n];
      }
      #pragma unroll
      for (int msk = 1; msk < 16; msk <<= 1){
        ps += __shfl_xor(ps, msk);
        pd += __shfl_xor(pd, msk);
      }
      int row = row0 + wr * 64 + m * 16 + kgrp * 4 + j;
      if (r15 == 0 && row < M){
        AS[(size_t)row * 8 + head] = ps;
        AD[(size_t)row * 8 + head] = pd;
      }
    }
  }
}

// ---------------- GAT aggregation: 2 dst streams/wave, max-only pass A, fused den+acc pass B ----------------
__global__ __launch_bounds__(256) void agg_f16(
    const _Float16* __restrict__ H16,
    const float* __restrict__ AS, const float* __restrict__ AD,
    const int* __restrict__ offsets, const int* __restrict__ csr_src,
    const float* __restrict__ bias, _Float16* __restrict__ O16, int N)
{
  const int wave = threadIdx.x >> 6, lane = threadIdx.x & 63;
  const int d0 = blockIdx.x * 8 + wave * 2;
  const int d1 = d0 + 1;
  const int h8 = lane & 7;
  const int hA = lane >> 3;

  int beg0 = 0, end0 = 0, beg1 = 0, end1 = 0;
  if (d0 < N){ beg0 = offsets[d0]; end0 = offsets[d0 + 1]; }
  if (d1 < N){ beg1 = offsets[d1]; end1 = offsets[d1 + 1]; }

  // ---- pass A: per-head max only (no exp, no rescale chain) ----
  float adv0 = (d0 < N) ? AD[(size_t)d0 * 8 + h8] : 0.f;
  float m0 = -1e30f;
  for (int sl = beg0 + hA; sl < end0; sl += 8){
    int s = csr_src[sl];
    m0 = fmaxf(m0, lrelu(AS[(size_t)s * 8 + h8] + adv0));
  }
  #pragma unroll
  for (int msk = 8; msk < 64; msk <<= 1) m0 = fmaxf(m0, __shfl_xor(m0, msk));
  const float mH0 = __shfl(m0, hA);
  const float aH0 = __shfl(adv0, hA);

  float adv1 = (d1 < N) ? AD[(size_t)d1 * 8 + h8] : 0.f;
  float m1 = -1e30f;
  for (int sl = beg1 + hA; sl < end1; sl += 8){
    int s = csr_src[sl];
    m1 = fmaxf(m1, lrelu(AS[(size_t)s * 8 + h8] + adv1));
  }
  #pragma unroll
  for (int msk = 8; msk < 64; msk <<= 1) m1 = fmaxf(m1, __shfl_xor(m1, msk));
  const float mH1 = __shfl(m1, hA);
  const float aH1 = __shfl(adv1, hA);

  // ---- pass B: interleaved dual-stream gather, fused den + acc ----
  f16x8 acc0 = splat8((_Float16)0.0f), acc1 = splat8((_Float16)0.0f);
  float den0 = 0.f, den1 = 0.f;
  const _Float16* Hb = H16 + lane * 8;
  int sl0 = beg0, sl1 = beg1;
  while (true){
    bool g0 = (sl0 + 4 <= end0);
    bool g1 = (sl1 + 4 <= end1);
    if (!g0 && !g1) break;
    int sa0=0,sb0=0,sc0=0,sd0=0, sa1=0,sb1=0,sc1=0,sd1=0;
    float pa0=0,pb0=0,pc0=0,pd0=0, pa1=0,pb1=0,pc1=0,pd1=0;
    f16x8 ua0,ub0,uc0,ud0, ua1,ub1,uc1,ud1;
    if (g0){
      sa0 = csr_src[sl0]; sb0 = csr_src[sl0+1]; sc0 = csr_src[sl0+2]; sd0 = csr_src[sl0+3];
      pa0 = AS[(size_t)sa0*8+hA]; pb0 = AS[(size_t)sb0*8+hA];
      pc0 = AS[(size_t)sc0*8+hA]; pd0 = AS[(size_t)sd0*8+hA];
      ua0 = *(const f16x8*)(Hb + (size_t)sa0*512); ub0 = *(const f16x8*)(Hb + (size_t)sb0*512);
      uc0 = *(const f16x8*)(Hb + (size_t)sc0*512); ud0 = *(const f16x8*)(Hb + (size_t)sd0*512);
    }
    if (g1){
      sa1 = csr_src[sl1]; sb1 = csr_src[sl1+1]; sc1 = csr_src[sl1+2]; sd1 = csr_src[sl1+3];
      pa1 = AS[(size_t)sa1*8+hA]; pb1 = AS[(size_t)sb1*8+hA];
      pc1 = AS[(size_t)sc1*8+hA]; pd1 = AS[(size_t)sd1*8+hA];
      ua1 = *(const f16x8*)(Hb + (size_t)sa1*512); ub1 = *(const f16x8*)(Hb + (size_t)sb1*512);
      uc1 = *(const f16x8*)(Hb + (size_t)sc1*512); ud1 = *(const f16x8*)(Hb + (size_t)sd1*512);
    }
    if (g0){
      float ea = __expf(lrelu(pa0 + aH0) - mH0);
      float eb = __expf(lrelu(pb0 + aH0) - mH0);
      float ec = __expf(lrelu(pc0 + aH0) - mH0);
      float ed = __expf(lrelu(pd0 + aH0) - mH0);
      den0 += (ea + eb) + (ec + ed);
      acc0 += splat8((_Float16)ea) * ua0;
      acc0 += splat8((_Float16)eb) * ub0;
      acc0 += splat8((_Float16)ec) * uc0;
      acc0 += splat8((_Float16)ed) * ud0;
      sl0 += 4;
    }
    if (g1){
      float ea = __expf(lrelu(pa1 + aH1) - mH1);
      float eb = __expf(lrelu(pb1 + aH1) - mH1);
      float ec = __expf(lrelu(pc1 + aH1) - mH1);
      float ed = __expf(lrelu(pd1 + aH1) - mH1);
      den1 += (ea + eb) + (ec + ed);
      acc1 += splat8((_Float16)ea) * ua1;
      acc1 += splat8((_Float16)eb) * ub1;
      acc1 += splat8((_Float16)ec) * uc1;
      acc1 += splat8((_Float16)ed) * ud1;
      sl1 += 4;
    }
  }
  for (; sl0 < end0; ++sl0){
    int s = csr_src[sl0];
    float p = AS[(size_t)s*8+hA];
    f16x8 u = *(const f16x8*)(Hb + (size_t)s*512);
    float e = __expf(lrelu(p + aH0) - mH0);
    den0 += e;
    acc0 += splat8((_Float16)e) * u;
  }
  for (; sl1 < end1; ++sl1){
    int s = csr_src[sl1];
    float p = AS[(size_t)s*8+hA];
    f16x8 u = *(const f16x8*)(Hb + (size_t)s*512);
    float e = __expf(lrelu(p + aH1) - mH1);
    den1 += e;
    acc1 += splat8((_Float16)e) * u;
  }

  const float4 b0 = *(const float4*)(bias + lane * 8);
  const float4 b1v = *(const float4*)(bias + lane * 8 + 4);
  float bb[8] = {b0.x, b0.y, b0.z, b0.w, b1v.x, b1v.y, b1v.z, b1v.w};
  if (d0 < N){
    float dAi = 1.f / fmaxf(den0, 1e-16f);
    H8U O;
    #pragma unroll
    for (int j = 0; j < 8; ++j) O.h[j] = (_Float16)elu1((float)acc0[j] * dAi + bb[j]);
    *(uint4*)(O16 + (size_t)d0 * 512 + lane * 8) = O.u;
  }
  if (d1 < N){
    float dAi = 1.f / fmaxf(den1, 1e-16f);
    H8U O;
    #pragma unroll
    for (int j = 0; j < 8; ++j) O.h[j] = (_Float16)elu1((float)acc1[j] * dAi + bb[j]);
    *(uint4*)(O16 + (size_t)d1 * 512 + lane * 8) = O.u;
  }
}

// ---------------- narrow GEMM + fused alpha3 ----------------
__global__ __launch_bounds__(256) void gemm_n16_f16(const _Float16* __restrict__ X, const float* __restrict__ W,
                                                    float* __restrict__ Y,
                                                    const float* __restrict__ a3s, const float* __restrict__ a3d,
                                                    float* __restrict__ AS3, float* __restrict__ AD3,
                                                    int M, int K){
  __shared__ float Ws[512 * 16];
  __shared__ float Xs[64][68];
  const int tid = threadIdx.x;
  for (int i = tid; i < K * 16; i += 256) Ws[i] = W[i];
  const int tx = tid & 15;
  const int ty = tid >> 4;
  const int row0 = blockIdx.x * 64;
  float acc[4] = {0.f, 0.f, 0.f, 0.f};
  for (int k0 = 0; k0 < K; k0 += 64){
    __syncthreads();
    #pragma unroll
    for (int it = 0; it < 2; ++it){
      int idx = it * 2048 + tid * 8;
      int r = idx >> 6, c = idx & 63;
      H8U U; U.u = *(const uint4*)(X + (size_t)(row0 + r) * K + k0 + c);
      float4 f0 = make_float4((float)U.h[0], (float)U.h[1], (float)U.h[2], (float)U.h[3]);
      float4 f1 = make_float4((float)U.h[4], (float)U.h[5], (float)U.h[6], (float)U.h[7]);
      *(float4*)&Xs[r][c] = f0;
      *(float4*)&Xs[r][c + 4] = f1;
    }
    __syncthreads();
    #pragma unroll
    for (int kk = 0; kk < 64; ++kk){
      float w = Ws[(k0 + kk) * 16 + tx];
      #pragma unroll
      for (int i = 0; i < 4; ++i) acc[i] += Xs[ty * 4 + i][kk] * w;
    }
  }
  const float sc = a3s[tx], dc = a3d[tx];
  #pragma unroll
  for (int i = 0; i < 4; ++i){
    int grow = row0 + ty * 4 + i;
    if (grow < M) Y[(size_t)grow * 16 + tx] = acc[i];
    float ps = acc[i] * sc, pd = acc[i] * dc;
    #pragma unroll
    for (int msk = 1; msk < 16; msk <<= 1){
      ps += __shfl_xor(ps, msk);
      pd += __shfl_xor(pd, msk);
    }
    if (tx == 0 && grow < M){ AS3[grow] = ps; AD3[grow] = pd; }
  }
}

// ---------------- layer-3 aggregation: max-only pass A, fused den+acc, log_softmax ----------------
__global__ __launch_bounds__(256) void agg3_kernel(
    const float* __restrict__ H3,
    const float* __restrict__ AS3, const float* __restrict__ AD3,
    const int* __restrict__ offsets, const int* __restrict__ csr_src,
    const float* __restrict__ bias, float* __restrict__ Out, int N)
{
  const int wave = threadIdx.x >> 6, lane = threadIdx.x & 63;
  const int d = blockIdx.x * 4 + wave;
  if (d >= N) return;
  const int beg = offsets[d], end = offsets[d + 1];
  const float adv = AD3[d];
  float m = -1e30f;
  for (int slot = beg + lane; slot < end; slot += 64){
    int s = csr_src[slot];
    m = fmaxf(m, lrelu(AS3[s] + adv));
  }
  #pragma unroll
  for (int msk = 1; msk < 64; msk <<= 1) m = fmaxf(m, __shfl_xor(m, msk));

  const int c = lane & 15;
  float acc = 0.f, den = 0.f;
  for (int slot = beg + (lane >> 4); slot < end; slot += 4){
    int s = csr_src[slot];
    float e = __expf(lrelu(AS3[s] + adv) - m);
    den += e;
    acc += e * H3[(size_t)s * 16 + c];
  }
  acc += __shfl_xor(acc, 16);
  acc += __shfl_xor(acc, 32);
  den += __shfl_xor(den, 16);
  den += __shfl_xor(den, 32);
  float v = acc / fmaxf(den, 1e-16f) + bias[c];
  float mm = v;
  #pragma unroll
  for (int msk = 1; msk < 16; msk <<= 1) mm = fmaxf(mm, __shfl_xor(mm, msk));
  float se = __expf(v - mm);
  #pragma unroll
  for (int msk = 1; msk < 16; msk <<= 1) se += __shfl_xor(se, msk);
  float r = v - mm - __logf(se);
  if (lane < 16) Out[(size_t)d * 16 + lane] = r;
}

extern "C" void kernel_launch(void* const* d_in, const int* in_sizes, int n_in,
                              void* d_out, int out_size, void* d_ws, size_t ws_size,
                              hipStream_t stream)
{
  const float* x   = (const float*)d_in[0];
  const int*   ei  = (const int*)d_in[1];
  const float* W1  = (const float*)d_in[2];
  const float* as1 = (const float*)d_in[3];
  const float* ad1 = (const float*)d_in[4];
  const float* b1  = (const float*)d_in[5];
  const float* W2  = (const float*)d_in[6];
  const float* as2 = (const float*)d_in[7];
  const float* ad2 = (const float*)d_in[8];
  const float* b2  = (const float*)d_in[9];
  const float* W3  = (const float*)d_in[10];
  const float* as3 = (const float*)d_in[11];
  const float* ad3 = (const float*)d_in[12];
  const float* b3  = (const float*)d_in[13];

  const int N    = in_sizes[0] / 256;
  const int E    = in_sizes[1] / 2;
  const int Et   = E + N;
  const int Mpad = (N + 127) & ~127;
  const int nb   = (N + 255) / 256;
  const int* src = ei;
  const int* dst = ei + E;

  char* base = (char*)d_ws;
  size_t off = 0;
  auto take = [&](size_t bytes) -> char* {
    char* p = base + off;
    off = (off + bytes + 255) & ~(size_t)255;
    return p;
  };
  _Float16* x16  = (_Float16*)take((size_t)Mpad * 256 * 2);
  _Float16* H16  = (_Float16*)take((size_t)Mpad * 512 * 2);
  _Float16* O16  = (_Float16*)take((size_t)Mpad * 512 * 2);
  _Float16* W1T  = (_Float16*)take((size_t)512 * 256 * 2);
  _Float16* W2T  = (_Float16*)take((size_t)512 * 512 * 2);
  float* AS   = (float*)take((size_t)N * 8 * 4);
  float* AD   = (float*)take((size_t)N * 8 * 4);
  float* H3   = (float*)take((size_t)N * 16 * 4);
  float* AS3  = (float*)take((size_t)N * 4);
  float* AD3  = (float*)take((size_t)N * 4);
  int* counts  = (int*)take((size_t)2 * N * 4);
  int* cursor  = counts + N;
  int* offsets = (int*)take((size_t)(N + 1) * 4);
  int* bsum    = (int*)take((size_t)(nb + 1) * 4);
  int* csr     = (int*)take((size_t)Et * 4);
  if (off > ws_size) return;

  hipMemsetAsync(counts, 0, (size_t)2 * N * 4, stream);
  const int tb = 256;
  const int cvtb = Mpad / 8;                 // convert blocks (Mpad*256/8/256)
  const int cntb = (Et + tb - 1) / tb;
  prep_kernel<<<cvtb + 384 + cntb, tb, 0, stream>>>(
      x, x16, cvtb, N * 256, Mpad * 256, W1, W1T, W2, W2T, dst, E, N, counts);
  block_sum_kernel<<<nb, 256, 0, stream>>>(counts, N, bsum);
  scan_bsum_kernel<<<1, 256, 0, stream>>>(bsum, nb, offsets, N);
  scan_within_kernel<<<nb, 256, 0, stream>>>(counts, bsum, offsets, N);
  fill_kernel<<<(Et + tb - 1) / tb, tb, 0, stream>>>(src, dst, E, N, offsets, cursor, csr);

  const int gM = Mpad / 128;
  // layer 1
  gemm_f16_mfma<<<dim3(gM, 4), 256, 0, stream>>>(x16, W1T, H16, as1, ad1, AS, AD, N, 512, 256);
  agg_f16<<<(N + 7) / 8, 256, 0, stream>>>(H16, AS, AD, offsets, csr, b1, O16, N);
  // layer 2
  gemm_f16_mfma<<<dim3(gM, 4), 256, 0, stream>>>(O16, W2T, H16, as2, ad2, AS, AD, N, 512, 512);
  agg_f16<<<(N + 7) / 8, 256, 0, stream>>>(H16, AS, AD, offsets, csr, b2, O16, N);
  // layer 3
  gemm_n16_f16<<<(N + 63) / 64, 256, 0, stream>>>(O16, W3, H3, as3, ad3, AS3, AD3, N, 512);
  agg3_kernel<<<(N + 3) / 4, 256, 0, stream>>>(H3, AS3, AD3, offsets, csr, b3, (float*)d_out, N);
}

// Round 6
// 237.895 us; speedup vs baseline: 1.1524x; 1.1524x over previous
//
#include <hip/hip_runtime.h>
#include <hip/hip_fp8.h>

#define NEG_SLOPE 0.2f

typedef _Float16 f16x8 __attribute__((ext_vector_type(8)));
typedef float f32x4 __attribute__((ext_vector_type(4)));
typedef float f32x2 __attribute__((ext_vector_type(2)));

#if defined(__has_builtin)
#if __has_builtin(__builtin_amdgcn_cvt_pk_f32_fp8)
#define HAVE_PK_FP8 1
#endif
#endif

__device__ __forceinline__ float lrelu(float x){ return x >= 0.0f ? x : NEG_SLOPE * x; }
__device__ __forceinline__ float elu1(float x){ return x > 0.0f ? x : __expf(x) - 1.0f; }

__device__ __forceinline__ void gload_lds16(const _Float16* g, _Float16* l){
  __builtin_amdgcn_global_load_lds(
      (const __attribute__((address_space(1))) unsigned int*)g,
      (__attribute__((address_space(3))) unsigned int*)l, 16, 0, 0);
}

__device__ __forceinline__ float f8_to_f32(unsigned char b){
  __hip_fp8_e4m3 t; t.__x = (__hip_fp8_storage_t)b; return (float)t;
}

__device__ __forceinline__ void dq8(uint2 u, float* f){
#ifdef HAVE_PK_FP8
  f32x2 a = __builtin_amdgcn_cvt_pk_f32_fp8(u.x, false);
  f32x2 b = __builtin_amdgcn_cvt_pk_f32_fp8(u.x, true);
  f32x2 c = __builtin_amdgcn_cvt_pk_f32_fp8(u.y, false);
  f32x2 d = __builtin_amdgcn_cvt_pk_f32_fp8(u.y, true);
  f[0]=a[0]; f[1]=a[1]; f[2]=b[0]; f[3]=b[1];
  f[4]=c[0]; f[5]=c[1]; f[6]=d[0]; f[7]=d[1];
#else
  const unsigned char* p = (const unsigned char*)&u;
  #pragma unroll
  for (int j = 0; j < 8; ++j) f[j] = f8_to_f32(p[j]);
#endif
}

union H8U { uint4 u; _Float16 h[8]; };

// ---------------- fused prep: convert x -> fp16, transpose W1/W2 -> fp16, count degrees ----------------
__global__ __launch_bounds__(256) void prep_kernel(
    const float* __restrict__ x, _Float16* __restrict__ x16, int cvtb, int valid, int total,
    const float* __restrict__ W1, _Float16* __restrict__ W1T,
    const float* __restrict__ W2, _Float16* __restrict__ W2T,
    const int* __restrict__ dstp, int E, int N, int* __restrict__ counts)
{
  __shared__ float tile[32][33];
  int b = blockIdx.x;
  const int tid = threadIdx.x;
  if (b < cvtb){
    int i = (b * 256 + tid) * 8;
    if (i < total){
      H8U o;
      if (i + 8 <= valid){
        float4 v0 = *(const float4*)(x + i);
        float4 v1 = *(const float4*)(x + i + 4);
        o.h[0] = (_Float16)v0.x; o.h[1] = (_Float16)v0.y; o.h[2] = (_Float16)v0.z; o.h[3] = (_Float16)v0.w;
        o.h[4] = (_Float16)v1.x; o.h[5] = (_Float16)v1.y; o.h[6] = (_Float16)v1.z; o.h[7] = (_Float16)v1.w;
      } else {
        #pragma unroll
        for (int j = 0; j < 8; ++j) o.h[j] = (i + j < valid) ? (_Float16)x[i + j] : (_Float16)0.0f;
      }
      *(uint4*)(x16 + i) = o.u;
    }
    return;
  }
  b -= cvtb;
  if (b < 128 + 256){
    const float* W; _Float16* WT; int K, Nn, bb;
    if (b < 128){ W = W1; WT = W1T; K = 256; Nn = 512; bb = b; }
    else        { W = W2; WT = W2T; K = 512; Nn = 512; bb = b - 128; }
    const int nbk = K / 32;
    const int k0 = (bb % nbk) * 32, n0 = (bb / nbk) * 32;
    const int tx = tid & 31, ty = tid >> 5;
    for (int i = ty; i < 32; i += 8)
      tile[i][tx] = W[(size_t)(k0 + i) * Nn + n0 + tx];
    __syncthreads();
    for (int i = ty; i < 32; i += 8)
      WT[(size_t)(n0 + i) * K + k0 + tx] = (_Float16)tile[tx][i];
    return;
  }
  b -= 384;
  {
    int i = b * 256 + tid;
    if (i < E + N){
      int d = (i < E) ? dstp[i] : (i - E);
      atomicAdd(&counts[d], 1);
    }
  }
}

// ---------------- CSR scan / fill ----------------
__global__ __launch_bounds__(256) void block_sum_kernel(const int* __restrict__ counts, int N, int* __restrict__ bsum){
  __shared__ int ws[4];
  const int lane = threadIdx.x & 63, wave = threadIdx.x >> 6;
  int i = blockIdx.x * 256 + threadIdx.x;
  int v = (i < N) ? counts[i] : 0;
  #pragma unroll
  for (int msk = 1; msk < 64; msk <<= 1) v += __shfl_xor(v, msk);
  if (lane == 0) ws[wave] = v;
  __syncthreads();
  if (threadIdx.x == 0) bsum[blockIdx.x] = ws[0] + ws[1] + ws[2] + ws[3];
}

__global__ __launch_bounds__(256) void scan_bsum_kernel(int* __restrict__ bsum, int nb, int* __restrict__ offsets, int N){
  __shared__ int tmp[256];
  const int t = threadIdx.x;
  int v = (t < nb) ? bsum[t] : 0;
  tmp[t] = v;
  __syncthreads();
  #pragma unroll
  for (int ofs = 1; ofs < 256; ofs <<= 1){
    int add = (t >= ofs) ? tmp[t - ofs] : 0;
    __syncthreads();
    tmp[t] += add;
    __syncthreads();
  }
  if (t < nb) bsum[t] = tmp[t] - v;          // exclusive
  if (t == nb - 1) offsets[N] = tmp[t];      // total
}

__global__ __launch_bounds__(256) void scan_within_kernel(const int* __restrict__ counts, const int* __restrict__ bsum,
                                                          int* __restrict__ offsets, int N){
  __shared__ int wsum[4];
  const int lane = threadIdx.x & 63, wave = threadIdx.x >> 6;
  int i = blockIdx.x * 256 + threadIdx.x;
  int v = (i < N) ? counts[i] : 0;
  int sc = v;
  #pragma unroll
  for (int ofs = 1; ofs < 64; ofs <<= 1){
    int t = __shfl_up(sc, ofs);
    if (lane >= ofs) sc += t;
  }
  if (lane == 63) wsum[wave] = sc;
  __syncthreads();
  int woff = 0;
  #pragma unroll
  for (int w = 0; w < 4; ++w) if (w < wave) woff += wsum[w];
  if (i < N) offsets[i] = bsum[blockIdx.x] + woff + sc - v;
}

__global__ void fill_kernel(const int* __restrict__ src, const int* __restrict__ dst, int E, int N,
                            const int* __restrict__ offsets, int* __restrict__ cursor, int* __restrict__ csr_src){
  int i = blockIdx.x * blockDim.x + threadIdx.x;
  if (i < E + N){
    int s, d;
    if (i < E){ s = src[i]; d = dst[i]; } else { s = i - E; d = i - E; }
    int pos = atomicAdd(&cursor[d], 1);
    csr_src[offsets[d] + pos] = s;
  }
}

// ---------------- fp16 MFMA GEMM + fused alpha + fp8 quantize epilogue ----------------
// Writes H8 (fp8 e4m3, per-(row,head) scaled) + SC scales + AS/AD. No fp16 C output.
__global__ __launch_bounds__(256) void gemm_f16_mfma_q(
    const _Float16* __restrict__ A, const _Float16* __restrict__ BT,
    unsigned char* __restrict__ H8, float* __restrict__ SC,
    const float* __restrict__ a_src, const float* __restrict__ a_dst,
    float* __restrict__ AS, float* __restrict__ AD,
    int M, int Nn, int K)
{
  __shared__ _Float16 As[128 * 64];
  __shared__ _Float16 Bs[128 * 64];
  const int tid = threadIdx.x;
  const int lane = tid & 63;
  const int wave = tid >> 6;
  const int wr = wave >> 1, wc = wave & 1;
  const int row0 = blockIdx.x * 128;
  const int col0 = blockIdx.y * 128;
  const int r15 = lane & 15;
  const int kgrp = lane >> 4;
  const int head = 2 * blockIdx.y + wc;   // this wave's 64-col head block

  f32x4 acc[4][4];
  #pragma unroll
  for (int m = 0; m < 4; ++m)
    #pragma unroll
    for (int n = 0; n < 4; ++n)
      acc[m][n] = (f32x4){0.f, 0.f, 0.f, 0.f};

  for (int k0 = 0; k0 < K; k0 += 64){
    #pragma unroll
    for (int it = 0; it < 4; ++it){
      int idx = it * 2048 + tid * 8;
      int r = idx >> 6, c = idx & 63;
      gload_lds16(A  + (size_t)(row0 + r) * K + k0 + c, &As[idx]);
      gload_lds16(BT + (size_t)(col0 + r) * K + k0 + c, &Bs[idx]);
    }
    __syncthreads();
    #pragma unroll
    for (int kk = 0; kk < 2; ++kk){
      const int cc = kk * 32 + kgrp * 8;
      f16x8 av[4], bv[4];
      #pragma unroll
      for (int q = 0; q < 4; ++q){
        av[q] = *(const f16x8*)&As[(wr * 64 + q * 16 + r15) * 64 + cc];
        bv[q] = *(const f16x8*)&Bs[(wc * 64 + q * 16 + r15) * 64 + cc];
      }
      #pragma unroll
      for (int m = 0; m < 4; ++m)
        #pragma unroll
        for (int n = 0; n < 4; ++n)
          acc[m][n] = __builtin_amdgcn_mfma_f32_16x16x32_f16(av[m], bv[n], acc[m][n], 0, 0, 0);
    }
    __syncthreads();
  }

  // alpha epilogue: wave owns head over its 64 rows x 64 cols
  float asv[4], adv[4];
  #pragma unroll
  for (int n = 0; n < 4; ++n){
    asv[n] = a_src[head * 64 + n * 16 + r15];
    adv[n] = a_dst[head * 64 + n * 16 + r15];
  }
  #pragma unroll
  for (int m = 0; m < 4; ++m){
    #pragma unroll
    for (int j = 0; j < 4; ++j){
      float ps = 0.f, pd = 0.f;
      #pragma unroll
      for (int n = 0; n < 4; ++n){
        float c = acc[m][n][j];
        ps += c * asv[n];
        pd += c * adv[n];
      }
      #pragma unroll
      for (int msk = 1; msk < 16; msk <<= 1){
        ps += __shfl_xor(ps, msk);
        pd += __shfl_xor(pd, msk);
      }
      int row = row0 + wr * 64 + m * 16 + kgrp * 4 + j;
      if (r15 == 0 && row < M){
        AS[(size_t)row * 8 + head] = ps;
        AD[(size_t)row * 8 + head] = pd;
      }
    }
  }

  // fp8 quantize epilogue: per-(row,head) scale; stage bytes via LDS (reuse As)
  unsigned char* stg = reinterpret_cast<unsigned char*>(As) + wave * 4096;
  #pragma unroll
  for (int m = 0; m < 4; ++m){
    #pragma unroll
    for (int j = 0; j < 4; ++j){
      float a = fmaxf(fmaxf(fabsf(acc[m][0][j]), fabsf(acc[m][1][j])),
                      fmaxf(fabsf(acc[m][2][j]), fabsf(acc[m][3][j])));
      #pragma unroll
      for (int msk = 1; msk < 16; msk <<= 1) a = fmaxf(a, __shfl_xor(a, msk));
      float inv = (a > 1e-30f) ? (448.0f / a) : 0.0f;
      int rm = m * 16 + kgrp * 4 + j;
      #pragma unroll
      for (int n = 0; n < 4; ++n){
        __hip_fp8_e4m3 q(acc[m][n][j] * inv);
        stg[rm * 64 + n * 16 + r15] = (unsigned char)q.__x;
      }
      if (r15 == 0){
        int row = row0 + wr * 64 + rm;
        SC[(size_t)row * 8 + head] = a * (1.0f / 448.0f);
      }
    }
  }
  // same-wave LDS read-back (no barrier needed: regions are wave-private)
  #pragma unroll
  for (int it = 0; it < 4; ++it){
    int srow = it * 16 + (lane >> 2);
    int chunk = lane & 3;
    uint4 v = *reinterpret_cast<const uint4*>(stg + srow * 64 + chunk * 16);
    int row = row0 + wr * 64 + srow;
    *reinterpret_cast<uint4*>(H8 + (size_t)row * 512 + head * 64 + chunk * 16) = v;
  }
}

// ---------------- GAT aggregation over fp8 H: 1 dst/wave, 4-deep gather, fp32 accumulate ----------------
__global__ __launch_bounds__(128) void agg_f8(
    const unsigned char* __restrict__ H8, const float* __restrict__ SC,
    const float* __restrict__ AS, const float* __restrict__ AD,
    const int* __restrict__ offsets, const int* __restrict__ csr_src,
    const float* __restrict__ bias, _Float16* __restrict__ O16, int N)
{
  const int wave = threadIdx.x >> 6, lane = threadIdx.x & 63;
  const int d = blockIdx.x * 2 + wave;
  if (d >= N) return;
  const int beg = offsets[d], end = offsets[d + 1];
  const int h8 = lane & 7;     // head this lane reduces in pass A
  const int hA = lane >> 3;    // head owning this lane's output channels
  const float adv = AD[(size_t)d * 8 + h8];

  // pass A: per-head max only
  float m = -1e30f;
  for (int sl = beg + hA; sl < end; sl += 8){
    int s = csr_src[sl];
    m = fmaxf(m, lrelu(AS[(size_t)s * 8 + h8] + adv));
  }
  #pragma unroll
  for (int msk = 8; msk < 64; msk <<= 1) m = fmaxf(m, __shfl_xor(m, msk));
  const float mH = __shfl(m, hA);
  const float aH = __shfl(adv, hA);

  // pass B: fused denom + accumulate, 4-deep batches
  float acc[8];
  #pragma unroll
  for (int j = 0; j < 8; ++j) acc[j] = 0.f;
  float den = 0.f;
  const unsigned char* Hb = H8 + lane * 8;
  int slot = beg;
  for (; slot + 4 <= end; slot += 4){
    int   s[4]; float p[4], c[4]; uint2 u[4];
    #pragma unroll
    for (int q = 0; q < 4; ++q) s[q] = csr_src[slot + q];
    #pragma unroll
    for (int q = 0; q < 4; ++q){ p[q] = AS[(size_t)s[q] * 8 + hA]; c[q] = SC[(size_t)s[q] * 8 + hA]; }
    #pragma unroll
    for (int q = 0; q < 4; ++q) u[q] = *(const uint2*)(Hb + (size_t)s[q] * 512);
    #pragma unroll
    for (int q = 0; q < 4; ++q){
      float e = __expf(lrelu(p[q] + aH) - mH);
      den += e;
      float w = e * c[q];
      float f[8];
      dq8(u[q], f);
      #pragma unroll
      for (int j = 0; j < 8; ++j) acc[j] += w * f[j];
    }
  }
  for (; slot < end; ++slot){
    int s0 = csr_src[slot];
    float p0 = AS[(size_t)s0 * 8 + hA];
    float c0 = SC[(size_t)s0 * 8 + hA];
    uint2 u0 = *(const uint2*)(Hb + (size_t)s0 * 512);
    float e = __expf(lrelu(p0 + aH) - mH);
    den += e;
    float w = e * c0;
    float f[8];
    dq8(u0, f);
    #pragma unroll
    for (int j = 0; j < 8; ++j) acc[j] += w * f[j];
  }

  const float di = 1.0f / fmaxf(den, 1e-16f);
  const float4 b0 = *(const float4*)(bias + lane * 8);
  const float4 b1 = *(const float4*)(bias + lane * 8 + 4);
  float bb[8] = {b0.x, b0.y, b0.z, b0.w, b1.x, b1.y, b1.z, b1.w};
  H8U O;
  #pragma unroll
  for (int j = 0; j < 8; ++j) O.h[j] = (_Float16)elu1(acc[j] * di + bb[j]);
  *(uint4*)(O16 + (size_t)d * 512 + lane * 8) = O.u;
}

// ---------------- narrow GEMM + fused alpha3 ----------------
__global__ __launch_bounds__(256) void gemm_n16_f16(const _Float16* __restrict__ X, const float* __restrict__ W,
                                                    float* __restrict__ Y,
                                                    const float* __restrict__ a3s, const float* __restrict__ a3d,
                                                    float* __restrict__ AS3, float* __restrict__ AD3,
                                                    int M, int K){
  __shared__ float Ws[512 * 16];
  __shared__ float Xs[64][68];
  const int tid = threadIdx.x;
  for (int i = tid; i < K * 16; i += 256) Ws[i] = W[i];
  const int tx = tid & 15;
  const int ty = tid >> 4;
  const int row0 = blockIdx.x * 64;
  float acc[4] = {0.f, 0.f, 0.f, 0.f};
  for (int k0 = 0; k0 < K; k0 += 64){
    __syncthreads();
    #pragma unroll
    for (int it = 0; it < 2; ++it){
      int idx = it * 2048 + tid * 8;
      int r = idx >> 6, c = idx & 63;
      H8U U; U.u = *(const uint4*)(X + (size_t)(row0 + r) * K + k0 + c);
      float4 f0 = make_float4((float)U.h[0], (float)U.h[1], (float)U.h[2], (float)U.h[3]);
      float4 f1 = make_float4((float)U.h[4], (float)U.h[5], (float)U.h[6], (float)U.h[7]);
      *(float4*)&Xs[r][c] = f0;
      *(float4*)&Xs[r][c + 4] = f1;
    }
    __syncthreads();
    #pragma unroll
    for (int kk = 0; kk < 64; ++kk){
      float w = Ws[(k0 + kk) * 16 + tx];
      #pragma unroll
      for (int i = 0; i < 4; ++i) acc[i] += Xs[ty * 4 + i][kk] * w;
    }
  }
  const float sc = a3s[tx], dc = a3d[tx];
  #pragma unroll
  for (int i = 0; i < 4; ++i){
    int grow = row0 + ty * 4 + i;
    if (grow < M) Y[(size_t)grow * 16 + tx] = acc[i];
    float ps = acc[i] * sc, pd = acc[i] * dc;
    #pragma unroll
    for (int msk = 1; msk < 16; msk <<= 1){
      ps += __shfl_xor(ps, msk);
      pd += __shfl_xor(pd, msk);
    }
    if (tx == 0 && grow < M){ AS3[grow] = ps; AD3[grow] = pd; }
  }
}

// ---------------- layer-3 aggregation: max-only pass A, fused den+acc, log_softmax ----------------
__global__ __launch_bounds__(256) void agg3_kernel(
    const float* __restrict__ H3,
    const float* __restrict__ AS3, const float* __restrict__ AD3,
    const int* __restrict__ offsets, const int* __restrict__ csr_src,
    const float* __restrict__ bias, float* __restrict__ Out, int N)
{
  const int wave = threadIdx.x >> 6, lane = threadIdx.x & 63;
  const int d = blockIdx.x * 4 + wave;
  if (d >= N) return;
  const int beg = offsets[d], end = offsets[d + 1];
  const float adv = AD3[d];
  float m = -1e30f;
  for (int slot = beg + lane; slot < end; slot += 64){
    int s = csr_src[slot];
    m = fmaxf(m, lrelu(AS3[s] + adv));
  }
  #pragma unroll
  for (int msk = 1; msk < 64; msk <<= 1) m = fmaxf(m, __shfl_xor(m, msk));

  const int c = lane & 15;
  float acc = 0.f, den = 0.f;
  for (int slot = beg + (lane >> 4); slot < end; slot += 4){
    int s = csr_src[slot];
    float e = __expf(lrelu(AS3[s] + adv) - m);
    den += e;
    acc += e * H3[(size_t)s * 16 + c];
  }
  acc += __shfl_xor(acc, 16);
  acc += __shfl_xor(acc, 32);
  den += __shfl_xor(den, 16);
  den += __shfl_xor(den, 32);
  float v = acc / fmaxf(den, 1e-16f) + bias[c];
  float mm = v;
  #pragma unroll
  for (int msk = 1; msk < 16; msk <<= 1) mm = fmaxf(mm, __shfl_xor(mm, msk));
  float se = __expf(v - mm);
  #pragma unroll
  for (int msk = 1; msk < 16; msk <<= 1) se += __shfl_xor(se, msk);
  float r = v - mm - __logf(se);
  if (lane < 16) Out[(size_t)d * 16 + lane] = r;
}

extern "C" void kernel_launch(void* const* d_in, const int* in_sizes, int n_in,
                              void* d_out, int out_size, void* d_ws, size_t ws_size,
                              hipStream_t stream)
{
  const float* x   = (const float*)d_in[0];
  const int*   ei  = (const int*)d_in[1];
  const float* W1  = (const float*)d_in[2];
  const float* as1 = (const float*)d_in[3];
  const float* ad1 = (const float*)d_in[4];
  const float* b1  = (const float*)d_in[5];
  const float* W2  = (const float*)d_in[6];
  const float* as2 = (const float*)d_in[7];
  const float* ad2 = (const float*)d_in[8];
  const float* b2  = (const float*)d_in[9];
  const float* W3  = (const float*)d_in[10];
  const float* as3 = (const float*)d_in[11];
  const float* ad3 = (const float*)d_in[12];
  const float* b3  = (const float*)d_in[13];

  const int N    = in_sizes[0] / 256;
  const int E    = in_sizes[1] / 2;
  const int Et   = E + N;
  const int Mpad = (N + 127) & ~127;
  const int nb   = (N + 255) / 256;
  const int* src = ei;
  const int* dst = ei + E;

  char* base = (char*)d_ws;
  size_t off = 0;
  auto take = [&](size_t bytes) -> char* {
    char* p = base + off;
    off = (off + bytes + 255) & ~(size_t)255;
    return p;
  };
  _Float16* x16  = (_Float16*)take((size_t)Mpad * 256 * 2);
  _Float16* O16  = (_Float16*)take((size_t)Mpad * 512 * 2);
  unsigned char* H8 = (unsigned char*)take((size_t)Mpad * 512);
  float* SC   = (float*)take((size_t)Mpad * 8 * 4);
  _Float16* W1T  = (_Float16*)take((size_t)512 * 256 * 2);
  _Float16* W2T  = (_Float16*)take((size_t)512 * 512 * 2);
  float* AS   = (float*)take((size_t)N * 8 * 4);
  float* AD   = (float*)take((size_t)N * 8 * 4);
  float* H3   = (float*)take((size_t)N * 16 * 4);
  float* AS3  = (float*)take((size_t)N * 4);
  float* AD3  = (float*)take((size_t)N * 4);
  int* counts  = (int*)take((size_t)2 * N * 4);
  int* cursor  = counts + N;
  int* offsets = (int*)take((size_t)(N + 1) * 4);
  int* bsum    = (int*)take((size_t)(nb + 1) * 4);
  int* csr     = (int*)take((size_t)Et * 4);
  if (off > ws_size) return;

  hipMemsetAsync(counts, 0, (size_t)2 * N * 4, stream);
  const int tb = 256;
  const int cvtb = Mpad / 8;
  const int cntb = (Et + tb - 1) / tb;
  prep_kernel<<<cvtb + 384 + cntb, tb, 0, stream>>>(
      x, x16, cvtb, N * 256, Mpad * 256, W1, W1T, W2, W2T, dst, E, N, counts);
  block_sum_kernel<<<nb, 256, 0, stream>>>(counts, N, bsum);
  scan_bsum_kernel<<<1, 256, 0, stream>>>(bsum, nb, offsets, N);
  scan_within_kernel<<<nb, 256, 0, stream>>>(counts, bsum, offsets, N);
  fill_kernel<<<(Et + tb - 1) / tb, tb, 0, stream>>>(src, dst, E, N, offsets, cursor, csr);

  const int gM = Mpad / 128;
  // layer 1
  gemm_f16_mfma_q<<<dim3(gM, 4), 256, 0, stream>>>(x16, W1T, H8, SC, as1, ad1, AS, AD, N, 512, 256);
  agg_f8<<<(N + 1) / 2, 128, 0, stream>>>(H8, SC, AS, AD, offsets, csr, b1, O16, N);
  // layer 2
  gemm_f16_mfma_q<<<dim3(gM, 4), 256, 0, stream>>>(O16, W2T, H8, SC, as2, ad2, AS, AD, N, 512, 512);
  agg_f8<<<(N + 1) / 2, 128, 0, stream>>>(H8, SC, AS, AD, offsets, csr, b2, O16, N);
  // layer 3
  gemm_n16_f16<<<(N + 63) / 64, 256, 0, stream>>>(O16, W3, H3, as3, ad3, AS3, AD3, N, 512);
  agg3_kernel<<<(N + 3) / 4, 256, 0, stream>>>(H3, AS3, AD3, offsets, csr, b3, (float*)d_out, N);
}

// Round 7
// 236.818 us; speedup vs baseline: 1.1576x; 1.0045x over previous
//
#include <hip/hip_runtime.h>
#include <hip/hip_fp8.h>

#define NEG_SLOPE 0.2f

typedef _Float16 f16x8 __attribute__((ext_vector_type(8)));
typedef float f32x4 __attribute__((ext_vector_type(4)));
typedef float f32x2 __attribute__((ext_vector_type(2)));

#if defined(__has_builtin)
#if __has_builtin(__builtin_amdgcn_cvt_pk_f32_fp8)
#define HAVE_PK_F32_FP8 1
#endif
#if __has_builtin(__builtin_amdgcn_cvt_pk_fp8_f32)
#define HAVE_PK_FP8_F32 1
#endif
#endif

__device__ __forceinline__ float lrelu(float x){ return x >= 0.0f ? x : NEG_SLOPE * x; }
__device__ __forceinline__ float elu1(float x){ return x > 0.0f ? x : __expf(x) - 1.0f; }

__device__ __forceinline__ void gload_lds16(const _Float16* g, _Float16* l){
  __builtin_amdgcn_global_load_lds(
      (const __attribute__((address_space(1))) unsigned int*)g,
      (__attribute__((address_space(3))) unsigned int*)l, 16, 0, 0);
}

__device__ __forceinline__ float f8_to_f32(unsigned char b){
  __hip_fp8_e4m3 t; t.__x = (__hip_fp8_storage_t)b; return (float)t;
}

// dword bytes k=0..3 -> f[k]; second dword -> f[4..7]
__device__ __forceinline__ void dq8(uint2 u, float* f){
#ifdef HAVE_PK_F32_FP8
  f32x2 a = __builtin_amdgcn_cvt_pk_f32_fp8(u.x, false);
  f32x2 b = __builtin_amdgcn_cvt_pk_f32_fp8(u.x, true);
  f32x2 c = __builtin_amdgcn_cvt_pk_f32_fp8(u.y, false);
  f32x2 d = __builtin_amdgcn_cvt_pk_f32_fp8(u.y, true);
  f[0]=a[0]; f[1]=a[1]; f[2]=b[0]; f[3]=b[1];
  f[4]=c[0]; f[5]=c[1]; f[6]=d[0]; f[7]=d[1];
#else
  const unsigned char* p = (const unsigned char*)&u;
  #pragma unroll
  for (int j = 0; j < 8; ++j) f[j] = f8_to_f32(p[j]);
#endif
}

__device__ __forceinline__ unsigned int pack4_fp8(float v0, float v1, float v2, float v3){
#ifdef HAVE_PK_FP8_F32
  int pk = __builtin_amdgcn_cvt_pk_fp8_f32(v0, v1, 0, false);
  pk = __builtin_amdgcn_cvt_pk_fp8_f32(v2, v3, pk, true);
  return (unsigned int)pk;
#else
  __hip_fp8_e4m3 q0(v0), q1(v1), q2(v2), q3(v3);
  return (unsigned int)q0.__x | ((unsigned int)q1.__x << 8) |
         ((unsigned int)q2.__x << 16) | ((unsigned int)q3.__x << 24);
#endif
}

union H8U { uint4 u; _Float16 h[8]; };
union P2U { _Float16 h[2]; unsigned int u; };

// ---------------- fused prep: convert x -> fp16, transpose W1/W2 -> fp16, count degrees ----------------
__global__ __launch_bounds__(256) void prep_kernel(
    const float* __restrict__ x, _Float16* __restrict__ x16, int cvtb, int valid, int total,
    const float* __restrict__ W1, _Float16* __restrict__ W1T,
    const float* __restrict__ W2, _Float16* __restrict__ W2T,
    const int* __restrict__ dstp, int E, int N, int* __restrict__ counts)
{
  __shared__ float tile[32][33];
  int b = blockIdx.x;
  const int tid = threadIdx.x;
  if (b < cvtb){
    int i = (b * 256 + tid) * 8;
    if (i < total){
      H8U o;
      if (i + 8 <= valid){
        float4 v0 = *(const float4*)(x + i);
        float4 v1 = *(const float4*)(x + i + 4);
        o.h[0] = (_Float16)v0.x; o.h[1] = (_Float16)v0.y; o.h[2] = (_Float16)v0.z; o.h[3] = (_Float16)v0.w;
        o.h[4] = (_Float16)v1.x; o.h[5] = (_Float16)v1.y; o.h[6] = (_Float16)v1.z; o.h[7] = (_Float16)v1.w;
      } else {
        #pragma unroll
        for (int j = 0; j < 8; ++j) o.h[j] = (i + j < valid) ? (_Float16)x[i + j] : (_Float16)0.0f;
      }
      *(uint4*)(x16 + i) = o.u;
    }
    return;
  }
  b -= cvtb;
  if (b < 128 + 256){
    const float* W; _Float16* WT; int K, Nn, bb;
    if (b < 128){ W = W1; WT = W1T; K = 256; Nn = 512; bb = b; }
    else        { W = W2; WT = W2T; K = 512; Nn = 512; bb = b - 128; }
    const int nbk = K / 32;
    const int k0 = (bb % nbk) * 32, n0 = (bb / nbk) * 32;
    const int tx = tid & 31, ty = tid >> 5;
    for (int i = ty; i < 32; i += 8)
      tile[i][tx] = W[(size_t)(k0 + i) * Nn + n0 + tx];
    __syncthreads();
    for (int i = ty; i < 32; i += 8)
      WT[(size_t)(n0 + i) * K + k0 + tx] = (_Float16)tile[tx][i];
    return;
  }
  b -= 384;
  {
    int i = b * 256 + tid;
    if (i < E + N){
      int d = (i < E) ? dstp[i] : (i - E);
      atomicAdd(&counts[d], 1);
    }
  }
}

// ---------------- CSR scan / fill ----------------
__global__ __launch_bounds__(256) void block_sum_kernel(const int* __restrict__ counts, int N, int* __restrict__ bsum){
  __shared__ int ws[4];
  const int lane = threadIdx.x & 63, wave = threadIdx.x >> 6;
  int i = blockIdx.x * 256 + threadIdx.x;
  int v = (i < N) ? counts[i] : 0;
  #pragma unroll
  for (int msk = 1; msk < 64; msk <<= 1) v += __shfl_xor(v, msk);
  if (lane == 0) ws[wave] = v;
  __syncthreads();
  if (threadIdx.x == 0) bsum[blockIdx.x] = ws[0] + ws[1] + ws[2] + ws[3];
}

__global__ __launch_bounds__(256) void scan_bsum_kernel(int* __restrict__ bsum, int nb, int* __restrict__ offsets, int N){
  __shared__ int tmp[256];
  const int t = threadIdx.x;
  int v = (t < nb) ? bsum[t] : 0;
  tmp[t] = v;
  __syncthreads();
  #pragma unroll
  for (int ofs = 1; ofs < 256; ofs <<= 1){
    int add = (t >= ofs) ? tmp[t - ofs] : 0;
    __syncthreads();
    tmp[t] += add;
    __syncthreads();
  }
  if (t < nb) bsum[t] = tmp[t] - v;
  if (t == nb - 1) offsets[N] = tmp[t];
}

__global__ __launch_bounds__(256) void scan_within_kernel(const int* __restrict__ counts, const int* __restrict__ bsum,
                                                          int* __restrict__ offsets, int N){
  __shared__ int wsum[4];
  const int lane = threadIdx.x & 63, wave = threadIdx.x >> 6;
  int i = blockIdx.x * 256 + threadIdx.x;
  int v = (i < N) ? counts[i] : 0;
  int sc = v;
  #pragma unroll
  for (int ofs = 1; ofs < 64; ofs <<= 1){
    int t = __shfl_up(sc, ofs);
    if (lane >= ofs) sc += t;
  }
  if (lane == 63) wsum[wave] = sc;
  __syncthreads();
  int woff = 0;
  #pragma unroll
  for (int w = 0; w < 4; ++w) if (w < wave) woff += wsum[w];
  if (i < N) offsets[i] = bsum[blockIdx.x] + woff + sc - v;
}

__global__ void fill_kernel(const int* __restrict__ src, const int* __restrict__ dst, int E, int N,
                            const int* __restrict__ offsets, int* __restrict__ cursor, int* __restrict__ csr_src){
  int i = blockIdx.x * blockDim.x + threadIdx.x;
  if (i < E + N){
    int s, d;
    if (i < E){ s = src[i]; d = dst[i]; } else { s = i - E; d = i - E; }
    int pos = atomicAdd(&cursor[d], 1);
    csr_src[offsets[d] + pos] = s;
  }
}

// ---------------- fp16 MFMA GEMM + fused alpha + fp8 quantize epilogue (no LDS, HW cvt) ----------------
// H8 row layout: per (row, head) 16 dwords; dword q holds cols {16k+q, k=0..3} (byte k -> col 16k+q).
__global__ __launch_bounds__(256) void gemm_f16_mfma_q(
    const _Float16* __restrict__ A, const _Float16* __restrict__ BT,
    unsigned char* __restrict__ H8, float* __restrict__ SC,
    const float* __restrict__ a_src, const float* __restrict__ a_dst,
    float* __restrict__ AS, float* __restrict__ AD,
    int M, int Nn, int K)
{
  __shared__ _Float16 As[128 * 64];
  __shared__ _Float16 Bs[128 * 64];
  const int tid = threadIdx.x;
  const int lane = tid & 63;
  const int wave = tid >> 6;
  const int wr = wave >> 1, wc = wave & 1;
  const int row0 = blockIdx.x * 128;
  const int col0 = blockIdx.y * 128;
  const int r15 = lane & 15;
  const int kgrp = lane >> 4;
  const int head = 2 * blockIdx.y + wc;

  f32x4 acc[4][4];
  #pragma unroll
  for (int m = 0; m < 4; ++m)
    #pragma unroll
    for (int n = 0; n < 4; ++n)
      acc[m][n] = (f32x4){0.f, 0.f, 0.f, 0.f};

  for (int k0 = 0; k0 < K; k0 += 64){
    #pragma unroll
    for (int it = 0; it < 4; ++it){
      int idx = it * 2048 + tid * 8;
      int r = idx >> 6, c = idx & 63;
      gload_lds16(A  + (size_t)(row0 + r) * K + k0 + c, &As[idx]);
      gload_lds16(BT + (size_t)(col0 + r) * K + k0 + c, &Bs[idx]);
    }
    __syncthreads();
    #pragma unroll
    for (int kk = 0; kk < 2; ++kk){
      const int cc = kk * 32 + kgrp * 8;
      f16x8 av[4], bv[4];
      #pragma unroll
      for (int q = 0; q < 4; ++q){
        av[q] = *(const f16x8*)&As[(wr * 64 + q * 16 + r15) * 64 + cc];
        bv[q] = *(const f16x8*)&Bs[(wc * 64 + q * 16 + r15) * 64 + cc];
      }
      #pragma unroll
      for (int m = 0; m < 4; ++m)
        #pragma unroll
        for (int n = 0; n < 4; ++n)
          acc[m][n] = __builtin_amdgcn_mfma_f32_16x16x32_f16(av[m], bv[n], acc[m][n], 0, 0, 0);
    }
    __syncthreads();
  }

  // alpha epilogue: wave owns `head` over its 64 rows
  float asv[4], adv[4];
  #pragma unroll
  for (int n = 0; n < 4; ++n){
    asv[n] = a_src[head * 64 + n * 16 + r15];
    adv[n] = a_dst[head * 64 + n * 16 + r15];
  }
  #pragma unroll
  for (int m = 0; m < 4; ++m){
    #pragma unroll
    for (int j = 0; j < 4; ++j){
      float ps = 0.f, pd = 0.f;
      #pragma unroll
      for (int n = 0; n < 4; ++n){
        float c = acc[m][n][j];
        ps += c * asv[n];
        pd += c * adv[n];
      }
      #pragma unroll
      for (int msk = 1; msk < 16; msk <<= 1){
        ps += __shfl_xor(ps, msk);
        pd += __shfl_xor(pd, msk);
      }
      int row = row0 + wr * 64 + m * 16 + kgrp * 4 + j;
      if (r15 == 0 && row < M){
        AS[(size_t)row * 8 + head] = ps;
        AD[(size_t)row * 8 + head] = pd;
      }
    }
  }

  // fp8 quantize epilogue: per-(row,head) scale, packed HW cvt, direct coalesced dword stores
  #pragma unroll
  for (int m = 0; m < 4; ++m){
    #pragma unroll
    for (int j = 0; j < 4; ++j){
      float a = fmaxf(fmaxf(fabsf(acc[m][0][j]), fabsf(acc[m][1][j])),
                      fmaxf(fabsf(acc[m][2][j]), fabsf(acc[m][3][j])));
      #pragma unroll
      for (int msk = 1; msk < 16; msk <<= 1) a = fmaxf(a, __shfl_xor(a, msk));
      float inv = (a > 1e-30f) ? (448.0f / a) : 0.0f;
      int row = row0 + wr * 64 + m * 16 + kgrp * 4 + j;
      unsigned int pk = pack4_fp8(acc[m][0][j] * inv, acc[m][1][j] * inv,
                                  acc[m][2][j] * inv, acc[m][3][j] * inv);
      *(unsigned int*)(H8 + (size_t)row * 512 + head * 64 + r15 * 4) = pk;
      if (r15 == 0) SC[(size_t)row * 8 + head] = a * (1.0f / 448.0f);
    }
  }
}

// ---------------- GAT aggregation over fp8 H: 1 dst/wave, 4-deep gather, fp32 accumulate ----------------
// lane = hA*8 + l3 reads dwords (2l3, 2l3+1) of head hA: f[k] -> col 16k+2l3, f[k+4] -> col 16k+2l3+1
__global__ __launch_bounds__(128) void agg_f8(
    const unsigned char* __restrict__ H8, const float* __restrict__ SC,
    const float* __restrict__ AS, const float* __restrict__ AD,
    const int* __restrict__ offsets, const int* __restrict__ csr_src,
    const float* __restrict__ bias, _Float16* __restrict__ O16, int N)
{
  const int wave = threadIdx.x >> 6, lane = threadIdx.x & 63;
  const int d = blockIdx.x * 2 + wave;
  if (d >= N) return;
  const int beg = offsets[d], end = offsets[d + 1];
  const int h8 = lane & 7;     // head this lane reduces in pass A
  const int hA = lane >> 3;    // head owning this lane's output channels
  const int l3 = lane & 7;
  const float adv = AD[(size_t)d * 8 + h8];

  // pass A: per-head max only
  float m = -1e30f;
  for (int sl = beg + hA; sl < end; sl += 8){
    int s = csr_src[sl];
    m = fmaxf(m, lrelu(AS[(size_t)s * 8 + h8] + adv));
  }
  #pragma unroll
  for (int msk = 8; msk < 64; msk <<= 1) m = fmaxf(m, __shfl_xor(m, msk));
  const float mH = __shfl(m, hA);
  const float aH = __shfl(adv, hA);

  // pass B: fused denom + accumulate, 4-deep batches
  float acc[8];
  #pragma unroll
  for (int j = 0; j < 8; ++j) acc[j] = 0.f;
  float den = 0.f;
  const unsigned char* Hb = H8 + lane * 8;
  int slot = beg;
  for (; slot + 4 <= end; slot += 4){
    int   s[4]; float p[4], c[4]; uint2 u[4];
    #pragma unroll
    for (int q = 0; q < 4; ++q) s[q] = csr_src[slot + q];
    #pragma unroll
    for (int q = 0; q < 4; ++q){ p[q] = AS[(size_t)s[q] * 8 + hA]; c[q] = SC[(size_t)s[q] * 8 + hA]; }
    #pragma unroll
    for (int q = 0; q < 4; ++q) u[q] = *(const uint2*)(Hb + (size_t)s[q] * 512);
    #pragma unroll
    for (int q = 0; q < 4; ++q){
      float e = __expf(lrelu(p[q] + aH) - mH);
      den += e;
      float w = e * c[q];
      float f[8];
      dq8(u[q], f);
      #pragma unroll
      for (int j = 0; j < 8; ++j) acc[j] += w * f[j];
    }
  }
  for (; slot < end; ++slot){
    int s0 = csr_src[slot];
    float p0 = AS[(size_t)s0 * 8 + hA];
    float c0 = SC[(size_t)s0 * 8 + hA];
    uint2 u0 = *(const uint2*)(Hb + (size_t)s0 * 512);
    float e = __expf(lrelu(p0 + aH) - mH);
    den += e;
    float w = e * c0;
    float f[8];
    dq8(u0, f);
    #pragma unroll
    for (int j = 0; j < 8; ++j) acc[j] += w * f[j];
  }

  const float di = 1.0f / fmaxf(den, 1e-16f);
  _Float16* Ob = O16 + (size_t)d * 512 + hA * 64 + 2 * l3;
  const float* Bb = bias + hA * 64 + 2 * l3;
  #pragma unroll
  for (int j = 0; j < 4; ++j){
    float2 bv = *(const float2*)(Bb + j * 16);
    P2U P;
    P.h[0] = (_Float16)elu1(acc[j] * di + bv.x);
    P.h[1] = (_Float16)elu1(acc[j + 4] * di + bv.y);
    *(unsigned int*)(Ob + j * 16) = P.u;
  }
}

// ---------------- narrow GEMM + fused alpha3 ----------------
__global__ __launch_bounds__(256) void gemm_n16_f16(const _Float16* __restrict__ X, const float* __restrict__ W,
                                                    float* __restrict__ Y,
                                                    const float* __restrict__ a3s, const float* __restrict__ a3d,
                                                    float* __restrict__ AS3, float* __restrict__ AD3,
                                                    int M, int K){
  __shared__ float Ws[512 * 16];
  __shared__ float Xs[64][68];
  const int tid = threadIdx.x;
  for (int i = tid; i < K * 16; i += 256) Ws[i] = W[i];
  const int tx = tid & 15;
  const int ty = tid >> 4;
  const int row0 = blockIdx.x * 64;
  float acc[4] = {0.f, 0.f, 0.f, 0.f};
  for (int k0 = 0; k0 < K; k0 += 64){
    __syncthreads();
    #pragma unroll
    for (int it = 0; it < 2; ++it){
      int idx = it * 2048 + tid * 8;
      int r = idx >> 6, c = idx & 63;
      H8U U; U.u = *(const uint4*)(X + (size_t)(row0 + r) * K + k0 + c);
      float4 f0 = make_float4((float)U.h[0], (float)U.h[1], (float)U.h[2], (float)U.h[3]);
      float4 f1 = make_float4((float)U.h[4], (float)U.h[5], (float)U.h[6], (float)U.h[7]);
      *(float4*)&Xs[r][c] = f0;
      *(float4*)&Xs[r][c + 4] = f1;
    }
    __syncthreads();
    #pragma unroll
    for (int kk = 0; kk < 64; ++kk){
      float w = Ws[(k0 + kk) * 16 + tx];
      #pragma unroll
      for (int i = 0; i < 4; ++i) acc[i] += Xs[ty * 4 + i][kk] * w;
    }
  }
  const float sc = a3s[tx], dc = a3d[tx];
  #pragma unroll
  for (int i = 0; i < 4; ++i){
    int grow = row0 + ty * 4 + i;
    if (grow < M) Y[(size_t)grow * 16 + tx] = acc[i];
    float ps = acc[i] * sc, pd = acc[i] * dc;
    #pragma unroll
    for (int msk = 1; msk < 16; msk <<= 1){
      ps += __shfl_xor(ps, msk);
      pd += __shfl_xor(pd, msk);
    }
    if (tx == 0 && grow < M){ AS3[grow] = ps; AD3[grow] = pd; }
  }
}

// ---------------- layer-3 aggregation: max-only pass A, fused den+acc, log_softmax ----------------
__global__ __launch_bounds__(256) void agg3_kernel(
    const float* __restrict__ H3,
    const float* __restrict__ AS3, const float* __restrict__ AD3,
    const int* __restrict__ offsets, const int* __restrict__ csr_src,
    const float* __restrict__ bias, float* __restrict__ Out, int N)
{
  const int wave = threadIdx.x >> 6, lane = threadIdx.x & 63;
  const int d = blockIdx.x * 4 + wave;
  if (d >= N) return;
  const int beg = offsets[d], end = offsets[d + 1];
  const float adv = AD3[d];
  float m = -1e30f;
  for (int slot = beg + lane; slot < end; slot += 64){
    int s = csr_src[slot];
    m = fmaxf(m, lrelu(AS3[s] + adv));
  }
  #pragma unroll
  for (int msk = 1; msk < 64; msk <<= 1) m = fmaxf(m, __shfl_xor(m, msk));

  const int c = lane & 15;
  float acc = 0.f, den = 0.f;
  for (int slot = beg + (lane >> 4); slot < end; slot += 4){
    int s = csr_src[slot];
    float e = __expf(lrelu(AS3[s] + adv) - m);
    den += e;
    acc += e * H3[(size_t)s * 16 + c];
  }
  acc += __shfl_xor(acc, 16);
  acc += __shfl_xor(acc, 32);
  den += __shfl_xor(den, 16);
  den += __shfl_xor(den, 32);
  float v = acc / fmaxf(den, 1e-16f) + bias[c];
  float mm = v;
  #pragma unroll
  for (int msk = 1; msk < 16; msk <<= 1) mm = fmaxf(mm, __shfl_xor(mm, msk));
  float se = __expf(v - mm);
  #pragma unroll
  for (int msk = 1; msk < 16; msk <<= 1) se += __shfl_xor(se, msk);
  float r = v - mm - __logf(se);
  if (lane < 16) Out[(size_t)d * 16 + lane] = r;
}

extern "C" void kernel_launch(void* const* d_in, const int* in_sizes, int n_in,
                              void* d_out, int out_size, void* d_ws, size_t ws_size,
                              hipStream_t stream)
{
  const float* x   = (const float*)d_in[0];
  const int*   ei  = (const int*)d_in[1];
  const float* W1  = (const float*)d_in[2];
  const float* as1 = (const float*)d_in[3];
  const float* ad1 = (const float*)d_in[4];
  const float* b1  = (const float*)d_in[5];
  const float* W2  = (const float*)d_in[6];
  const float* as2 = (const float*)d_in[7];
  const float* ad2 = (const float*)d_in[8];
  const float* b2  = (const float*)d_in[9];
  const float* W3  = (const float*)d_in[10];
  const float* as3 = (const float*)d_in[11];
  const float* ad3 = (const float*)d_in[12];
  const float* b3  = (const float*)d_in[13];

  const int N    = in_sizes[0] / 256;
  const int E    = in_sizes[1] / 2;
  const int Et   = E + N;
  const int Mpad = (N + 127) & ~127;
  const int nb   = (N + 255) / 256;
  const int* src = ei;
  const int* dst = ei + E;

  char* base = (char*)d_ws;
  size_t off = 0;
  auto take = [&](size_t bytes) -> char* {
    char* p = base + off;
    off = (off + bytes + 255) & ~(size_t)255;
    return p;
  };
  _Float16* x16  = (_Float16*)take((size_t)Mpad * 256 * 2);
  _Float16* O16  = (_Float16*)take((size_t)Mpad * 512 * 2);
  unsigned char* H8 = (unsigned char*)take((size_t)Mpad * 512);
  float* SC   = (float*)take((size_t)Mpad * 8 * 4);
  _Float16* W1T  = (_Float16*)take((size_t)512 * 256 * 2);
  _Float16* W2T  = (_Float16*)take((size_t)512 * 512 * 2);
  float* AS   = (float*)take((size_t)N * 8 * 4);
  float* AD   = (float*)take((size_t)N * 8 * 4);
  float* H3   = (float*)take((size_t)N * 16 * 4);
  float* AS3  = (float*)take((size_t)N * 4);
  float* AD3  = (float*)take((size_t)N * 4);
  int* counts  = (int*)take((size_t)2 * N * 4);
  int* cursor  = counts + N;
  int* offsets = (int*)take((size_t)(N + 1) * 4);
  int* bsum    = (int*)take((size_t)(nb + 1) * 4);
  int* csr     = (int*)take((size_t)Et * 4);
  if (off > ws_size) return;

  hipMemsetAsync(counts, 0, (size_t)2 * N * 4, stream);
  const int tb = 256;
  const int cvtb = Mpad / 8;
  const int cntb = (Et + tb - 1) / tb;
  prep_kernel<<<cvtb + 384 + cntb, tb, 0, stream>>>(
      x, x16, cvtb, N * 256, Mpad * 256, W1, W1T, W2, W2T, dst, E, N, counts);
  block_sum_kernel<<<nb, 256, 0, stream>>>(counts, N, bsum);
  scan_bsum_kernel<<<1, 256, 0, stream>>>(bsum, nb, offsets, N);
  scan_within_kernel<<<nb, 256, 0, stream>>>(counts, bsum, offsets, N);
  fill_kernel<<<(Et + tb - 1) / tb, tb, 0, stream>>>(src, dst, E, N, offsets, cursor, csr);

  const int gM = Mpad / 128;
  // layer 1
  gemm_f16_mfma_q<<<dim3(gM, 4), 256, 0, stream>>>(x16, W1T, H8, SC, as1, ad1, AS, AD, N, 512, 256);
  agg_f8<<<(N + 1) / 2, 128, 0, stream>>>(H8, SC, AS, AD, offsets, csr, b1, O16, N);
  // layer 2
  gemm_f16_mfma_q<<<dim3(gM, 4), 256, 0, stream>>>(O16, W2T, H8, SC, as2, ad2, AS, AD, N, 512, 512);
  agg_f8<<<(N + 1) / 2, 128, 0, stream>>>(H8, SC, AS, AD, offsets, csr, b2, O16, N);
  // layer 3
  gemm_n16_f16<<<(N + 63) / 64, 256, 0, stream>>>(O16, W3, H3, as3, ad3, AS3, AD3, N, 512);
  agg3_kernel<<<(N + 3) / 4, 256, 0, stream>>>(H3, AS3, AD3, offsets, csr, b3, (float*)d_out, N);
}

// Round 8
// 217.426 us; speedup vs baseline: 1.2608x; 1.0892x over previous
//
#include <hip/hip_runtime.h>
#include <hip/hip_fp8.h>

#define NEG_SLOPE 0.2f

typedef _Float16 f16x8 __attribute__((ext_vector_type(8)));
typedef float f32x4 __attribute__((ext_vector_type(4)));
typedef float f32x2 __attribute__((ext_vector_type(2)));

#if defined(__has_builtin)
#if __has_builtin(__builtin_amdgcn_cvt_pk_f32_fp8)
#define HAVE_PK_F32_FP8 1
#endif
#if __has_builtin(__builtin_amdgcn_cvt_pk_fp8_f32)
#define HAVE_PK_FP8_F32 1
#endif
#endif

__device__ __forceinline__ float lrelu(float x){ return x >= 0.0f ? x : NEG_SLOPE * x; }
__device__ __forceinline__ float elu1(float x){ return x > 0.0f ? x : __expf(x) - 1.0f; }

__device__ __forceinline__ void gload_lds16(const _Float16* g, _Float16* l){
  __builtin_amdgcn_global_load_lds(
      (const __attribute__((address_space(1))) unsigned int*)g,
      (__attribute__((address_space(3))) unsigned int*)l, 16, 0, 0);
}

__device__ __forceinline__ float f8_to_f32(unsigned char b){
  __hip_fp8_e4m3 t; t.__x = (__hip_fp8_storage_t)b; return (float)t;
}

// dword bytes k=0..3 -> f[k]; second dword -> f[4..7]
__device__ __forceinline__ void dq8(uint2 u, float* f){
#ifdef HAVE_PK_F32_FP8
  f32x2 a = __builtin_amdgcn_cvt_pk_f32_fp8(u.x, false);
  f32x2 b = __builtin_amdgcn_cvt_pk_f32_fp8(u.x, true);
  f32x2 c = __builtin_amdgcn_cvt_pk_f32_fp8(u.y, false);
  f32x2 d = __builtin_amdgcn_cvt_pk_f32_fp8(u.y, true);
  f[0]=a[0]; f[1]=a[1]; f[2]=b[0]; f[3]=b[1];
  f[4]=c[0]; f[5]=c[1]; f[6]=d[0]; f[7]=d[1];
#else
  const unsigned char* p = (const unsigned char*)&u;
  #pragma unroll
  for (int j = 0; j < 8; ++j) f[j] = f8_to_f32(p[j]);
#endif
}

__device__ __forceinline__ unsigned int pack4_fp8(float v0, float v1, float v2, float v3){
#ifdef HAVE_PK_FP8_F32
  int pk = __builtin_amdgcn_cvt_pk_fp8_f32(v0, v1, 0, false);
  pk = __builtin_amdgcn_cvt_pk_fp8_f32(v2, v3, pk, true);
  return (unsigned int)pk;
#else
  __hip_fp8_e4m3 q0(v0), q1(v1), q2(v2), q3(v3);
  return (unsigned int)q0.__x | ((unsigned int)q1.__x << 8) |
         ((unsigned int)q2.__x << 16) | ((unsigned int)q3.__x << 24);
#endif
}

union H8U { uint4 u; _Float16 h[8]; };
union P2U { _Float16 h[2]; unsigned int u; };

// ---------------- fused prep: convert x -> fp16, transpose W1/W2 -> fp16, count degrees ----------------
__global__ __launch_bounds__(256) void prep_kernel(
    const float* __restrict__ x, _Float16* __restrict__ x16, int cvtb, int valid, int total,
    const float* __restrict__ W1, _Float16* __restrict__ W1T,
    const float* __restrict__ W2, _Float16* __restrict__ W2T,
    const int* __restrict__ dstp, int E, int N, int* __restrict__ counts)
{
  __shared__ float tile[32][33];
  int b = blockIdx.x;
  const int tid = threadIdx.x;
  if (b < cvtb){
    int i = (b * 256 + tid) * 8;
    if (i < total){
      H8U o;
      if (i + 8 <= valid){
        float4 v0 = *(const float4*)(x + i);
        float4 v1 = *(const float4*)(x + i + 4);
        o.h[0] = (_Float16)v0.x; o.h[1] = (_Float16)v0.y; o.h[2] = (_Float16)v0.z; o.h[3] = (_Float16)v0.w;
        o.h[4] = (_Float16)v1.x; o.h[5] = (_Float16)v1.y; o.h[6] = (_Float16)v1.z; o.h[7] = (_Float16)v1.w;
      } else {
        #pragma unroll
        for (int j = 0; j < 8; ++j) o.h[j] = (i + j < valid) ? (_Float16)x[i + j] : (_Float16)0.0f;
      }
      *(uint4*)(x16 + i) = o.u;
    }
    return;
  }
  b -= cvtb;
  if (b < 128 + 256){
    const float* W; _Float16* WT; int K, Nn, bb;
    if (b < 128){ W = W1; WT = W1T; K = 256; Nn = 512; bb = b; }
    else        { W = W2; WT = W2T; K = 512; Nn = 512; bb = b - 128; }
    const int nbk = K / 32;
    const int k0 = (bb % nbk) * 32, n0 = (bb / nbk) * 32;
    const int tx = tid & 31, ty = tid >> 5;
    for (int i = ty; i < 32; i += 8)
      tile[i][tx] = W[(size_t)(k0 + i) * Nn + n0 + tx];
    __syncthreads();
    for (int i = ty; i < 32; i += 8)
      WT[(size_t)(n0 + i) * K + k0 + tx] = (_Float16)tile[tx][i];
    return;
  }
  b -= 384;
  {
    int i = b * 256 + tid;
    if (i < E + N){
      int d = (i < E) ? dstp[i] : (i - E);
      atomicAdd(&counts[d], 1);
    }
  }
}

// ---------------- CSR scan / fill ----------------
__global__ __launch_bounds__(256) void block_sum_kernel(const int* __restrict__ counts, int N, int* __restrict__ bsum){
  __shared__ int ws[4];
  const int lane = threadIdx.x & 63, wave = threadIdx.x >> 6;
  int i = blockIdx.x * 256 + threadIdx.x;
  int v = (i < N) ? counts[i] : 0;
  #pragma unroll
  for (int msk = 1; msk < 64; msk <<= 1) v += __shfl_xor(v, msk);
  if (lane == 0) ws[wave] = v;
  __syncthreads();
  if (threadIdx.x == 0) bsum[blockIdx.x] = ws[0] + ws[1] + ws[2] + ws[3];
}

__global__ __launch_bounds__(256) void scan_bsum_kernel(int* __restrict__ bsum, int nb, int* __restrict__ offsets, int N){
  __shared__ int tmp[256];
  const int t = threadIdx.x;
  int v = (t < nb) ? bsum[t] : 0;
  tmp[t] = v;
  __syncthreads();
  #pragma unroll
  for (int ofs = 1; ofs < 256; ofs <<= 1){
    int add = (t >= ofs) ? tmp[t - ofs] : 0;
    __syncthreads();
    tmp[t] += add;
    __syncthreads();
  }
  if (t < nb) bsum[t] = tmp[t] - v;
  if (t == nb - 1) offsets[N] = tmp[t];
}

__global__ __launch_bounds__(256) void scan_within_kernel(const int* __restrict__ counts, const int* __restrict__ bsum,
                                                          int* __restrict__ offsets, int N){
  __shared__ int wsum[4];
  const int lane = threadIdx.x & 63, wave = threadIdx.x >> 6;
  int i = blockIdx.x * 256 + threadIdx.x;
  int v = (i < N) ? counts[i] : 0;
  int sc = v;
  #pragma unroll
  for (int ofs = 1; ofs < 64; ofs <<= 1){
    int t = __shfl_up(sc, ofs);
    if (lane >= ofs) sc += t;
  }
  if (lane == 63) wsum[wave] = sc;
  __syncthreads();
  int woff = 0;
  #pragma unroll
  for (int w = 0; w < 4; ++w) if (w < wave) woff += wsum[w];
  if (i < N) offsets[i] = bsum[blockIdx.x] + woff + sc - v;
}

__global__ void fill_kernel(const int* __restrict__ src, const int* __restrict__ dst, int E, int N,
                            const int* __restrict__ offsets, int* __restrict__ cursor, int* __restrict__ csr_src){
  int i = blockIdx.x * blockDim.x + threadIdx.x;
  if (i < E + N){
    int s, d;
    if (i < E){ s = src[i]; d = dst[i]; } else { s = i - E; d = i - E; }
    int pos = atomicAdd(&cursor[d], 1);
    csr_src[offsets[d] + pos] = s;
  }
}

// ---------------- fp16 MFMA GEMM (64x128 tile, XOR-swizzled LDS) + fused alpha + fp8 quantize ----------------
// LDS chunk (r, c) holds global chunk (c ^ (r&7)) of row r  [chunk = 16B = 8 f16]
// H8 row layout: per (row, head) 16 dwords; dword q holds cols {16k+q, k=0..3}.
__global__ __launch_bounds__(256) void gemm_f16_mfma_q(
    const _Float16* __restrict__ A, const _Float16* __restrict__ BT,
    unsigned char* __restrict__ H8, float* __restrict__ SC,
    const float* __restrict__ a_src, const float* __restrict__ a_dst,
    float* __restrict__ AS, float* __restrict__ AD,
    int M, int Nn, int K)
{
  __shared__ _Float16 As[64 * 64];    // 8 KB
  __shared__ _Float16 Bs[128 * 64];   // 16 KB
  const int tid = threadIdx.x;
  const int lane = tid & 63;
  const int wave = tid >> 6;
  const int wr = wave >> 1, wc = wave & 1;   // wave: 32 rows x 64 cols
  const int row0 = blockIdx.x * 64;
  const int col0 = blockIdx.y * 128;
  const int r15 = lane & 15;
  const int kgrp = lane >> 4;
  const int head = 2 * blockIdx.y + wc;
  const int sw = r15 & 7;                    // read-side XOR swizzle

  f32x4 acc[2][4];
  #pragma unroll
  for (int m = 0; m < 2; ++m)
    #pragma unroll
    for (int n = 0; n < 4; ++n)
      acc[m][n] = (f32x4){0.f, 0.f, 0.f, 0.f};

  for (int k0 = 0; k0 < K; k0 += 64){
    #pragma unroll
    for (int it = 0; it < 2; ++it){
      int ci = it * 256 + tid;
      int r = ci >> 3, ch = (ci & 7) ^ (r & 7);
      gload_lds16(A + (size_t)(row0 + r) * K + k0 + ch * 8, &As[ci * 8]);
    }
    #pragma unroll
    for (int it = 0; it < 4; ++it){
      int ci = it * 256 + tid;
      int r = ci >> 3, ch = (ci & 7) ^ (r & 7);
      gload_lds16(BT + (size_t)(col0 + r) * K + k0 + ch * 8, &Bs[ci * 8]);
    }
    __syncthreads();
    #pragma unroll
    for (int kk = 0; kk < 2; ++kk){
      f16x8 av[2], bv[4];
      #pragma unroll
      for (int q = 0; q < 2; ++q){
        int rr = wr * 32 + q * 16 + r15;
        av[q] = *(const f16x8*)&As[rr * 64 + (((kgrp + kk * 4) ^ sw) * 8)];
      }
      #pragma unroll
      for (int q = 0; q < 4; ++q){
        int rr = wc * 64 + q * 16 + r15;
        bv[q] = *(const f16x8*)&Bs[rr * 64 + (((kgrp + kk * 4) ^ sw) * 8)];
      }
      #pragma unroll
      for (int m = 0; m < 2; ++m)
        #pragma unroll
        for (int n = 0; n < 4; ++n)
          acc[m][n] = __builtin_amdgcn_mfma_f32_16x16x32_f16(av[m], bv[n], acc[m][n], 0, 0, 0);
    }
    __syncthreads();
  }

  // alpha epilogue: wave owns `head` over its 32 rows
  float asv[4], adv[4];
  #pragma unroll
  for (int n = 0; n < 4; ++n){
    asv[n] = a_src[head * 64 + n * 16 + r15];
    adv[n] = a_dst[head * 64 + n * 16 + r15];
  }
  #pragma unroll
  for (int m = 0; m < 2; ++m){
    #pragma unroll
    for (int j = 0; j < 4; ++j){
      float ps = 0.f, pd = 0.f;
      #pragma unroll
      for (int n = 0; n < 4; ++n){
        float c = acc[m][n][j];
        ps += c * asv[n];
        pd += c * adv[n];
      }
      #pragma unroll
      for (int msk = 1; msk < 16; msk <<= 1){
        ps += __shfl_xor(ps, msk);
        pd += __shfl_xor(pd, msk);
      }
      int row = row0 + wr * 32 + m * 16 + kgrp * 4 + j;
      if (r15 == 0 && row < M){
        AS[(size_t)row * 8 + head] = ps;
        AD[(size_t)row * 8 + head] = pd;
      }
    }
  }

  // fp8 quantize epilogue: per-(row,head) scale, packed HW cvt, coalesced dword stores
  #pragma unroll
  for (int m = 0; m < 2; ++m){
    #pragma unroll
    for (int j = 0; j < 4; ++j){
      float a = fmaxf(fmaxf(fabsf(acc[m][0][j]), fabsf(acc[m][1][j])),
                      fmaxf(fabsf(acc[m][2][j]), fabsf(acc[m][3][j])));
      #pragma unroll
      for (int msk = 1; msk < 16; msk <<= 1) a = fmaxf(a, __shfl_xor(a, msk));
      float inv = (a > 1e-30f) ? (448.0f / a) : 0.0f;
      int row = row0 + wr * 32 + m * 16 + kgrp * 4 + j;
      unsigned int pk = pack4_fp8(acc[m][0][j] * inv, acc[m][1][j] * inv,
                                  acc[m][2][j] * inv, acc[m][3][j] * inv);
      *(unsigned int*)(H8 + (size_t)row * 512 + head * 64 + r15 * 4) = pk;
      if (r15 == 0) SC[(size_t)row * 8 + head] = a * (1.0f / 448.0f);
    }
  }
}

// ---------------- GAT aggregation over fp8 H: 1 dst/wave, 4-deep gather, fp32 accumulate ----------------
// lane = hA*8 + l3 reads dwords (2l3, 2l3+1) of head hA: f[k] -> col 16k+2l3, f[k+4] -> col 16k+2l3+1
__global__ __launch_bounds__(128) void agg_f8(
    const unsigned char* __restrict__ H8, const float* __restrict__ SC,
    const float* __restrict__ AS, const float* __restrict__ AD,
    const int* __restrict__ offsets, const int* __restrict__ csr_src,
    const float* __restrict__ bias, _Float16* __restrict__ O16, int N)
{
  const int wave = threadIdx.x >> 6, lane = threadIdx.x & 63;
  const int d = blockIdx.x * 2 + wave;
  if (d >= N) return;
  const int beg = offsets[d], end = offsets[d + 1];
  const int h8 = lane & 7;     // head this lane reduces in pass A
  const int hA = lane >> 3;    // head owning this lane's output channels
  const int l3 = lane & 7;
  const float adv = AD[(size_t)d * 8 + h8];

  // pass A: per-head max only
  float m = -1e30f;
  for (int sl = beg + hA; sl < end; sl += 8){
    int s = csr_src[sl];
    m = fmaxf(m, lrelu(AS[(size_t)s * 8 + h8] + adv));
  }
  #pragma unroll
  for (int msk = 8; msk < 64; msk <<= 1) m = fmaxf(m, __shfl_xor(m, msk));
  const float mH = __shfl(m, hA);
  const float aH = __shfl(adv, hA);

  // pass B: fused denom + accumulate, 4-deep batches
  float acc[8];
  #pragma unroll
  for (int j = 0; j < 8; ++j) acc[j] = 0.f;
  float den = 0.f;
  const unsigned char* Hb = H8 + lane * 8;
  int slot = beg;
  for (; slot + 4 <= end; slot += 4){
    int   s[4]; float p[4], c[4]; uint2 u[4];
    #pragma unroll
    for (int q = 0; q < 4; ++q) s[q] = csr_src[slot + q];
    #pragma unroll
    for (int q = 0; q < 4; ++q){ p[q] = AS[(size_t)s[q] * 8 + hA]; c[q] = SC[(size_t)s[q] * 8 + hA]; }
    #pragma unroll
    for (int q = 0; q < 4; ++q) u[q] = *(const uint2*)(Hb + (size_t)s[q] * 512);
    #pragma unroll
    for (int q = 0; q < 4; ++q){
      float e = __expf(lrelu(p[q] + aH) - mH);
      den += e;
      float w = e * c[q];
      float f[8];
      dq8(u[q], f);
      #pragma unroll
      for (int j = 0; j < 8; ++j) acc[j] += w * f[j];
    }
  }
  for (; slot < end; ++slot){
    int s0 = csr_src[slot];
    float p0 = AS[(size_t)s0 * 8 + hA];
    float c0 = SC[(size_t)s0 * 8 + hA];
    uint2 u0 = *(const uint2*)(Hb + (size_t)s0 * 512);
    float e = __expf(lrelu(p0 + aH) - mH);
    den += e;
    float w = e * c0;
    float f[8];
    dq8(u0, f);
    #pragma unroll
    for (int j = 0; j < 8; ++j) acc[j] += w * f[j];
  }

  const float di = 1.0f / fmaxf(den, 1e-16f);
  _Float16* Ob = O16 + (size_t)d * 512 + hA * 64 + 2 * l3;
  const float* Bb = bias + hA * 64 + 2 * l3;
  #pragma unroll
  for (int j = 0; j < 4; ++j){
    float2 bv = *(const float2*)(Bb + j * 16);
    P2U P;
    P.h[0] = (_Float16)elu1(acc[j] * di + bv.x);
    P.h[1] = (_Float16)elu1(acc[j + 4] * di + bv.y);
    *(unsigned int*)(Ob + j * 16) = P.u;
  }
}

// ---------------- narrow GEMM + fused alpha3 ----------------
__global__ __launch_bounds__(256) void gemm_n16_f16(const _Float16* __restrict__ X, const float* __restrict__ W,
                                                    float* __restrict__ Y,
                                                    const float* __restrict__ a3s, const float* __restrict__ a3d,
                                                    float* __restrict__ AS3, float* __restrict__ AD3,
                                                    int M, int K){
  __shared__ float Ws[512 * 16];
  __shared__ float Xs[64][68];
  const int tid = threadIdx.x;
  for (int i = tid; i < K * 16; i += 256) Ws[i] = W[i];
  const int tx = tid & 15;
  const int ty = tid >> 4;
  const int row0 = blockIdx.x * 64;
  float acc[4] = {0.f, 0.f, 0.f, 0.f};
  for (int k0 = 0; k0 < K; k0 += 64){
    __syncthreads();
    #pragma unroll
    for (int it = 0; it < 2; ++it){
      int idx = it * 2048 + tid * 8;
      int r = idx >> 6, c = idx & 63;
      H8U U; U.u = *(const uint4*)(X + (size_t)(row0 + r) * K + k0 + c);
      float4 f0 = make_float4((float)U.h[0], (float)U.h[1], (float)U.h[2], (float)U.h[3]);
      float4 f1 = make_float4((float)U.h[4], (float)U.h[5], (float)U.h[6], (float)U.h[7]);
      *(float4*)&Xs[r][c] = f0;
      *(float4*)&Xs[r][c + 4] = f1;
    }
    __syncthreads();
    #pragma unroll
    for (int kk = 0; kk < 64; ++kk){
      float w = Ws[(k0 + kk) * 16 + tx];
      #pragma unroll
      for (int i = 0; i < 4; ++i) acc[i] += Xs[ty * 4 + i][kk] * w;
    }
  }
  const float sc = a3s[tx], dc = a3d[tx];
  #pragma unroll
  for (int i = 0; i < 4; ++i){
    int grow = row0 + ty * 4 + i;
    if (grow < M) Y[(size_t)grow * 16 + tx] = acc[i];
    float ps = acc[i] * sc, pd = acc[i] * dc;
    #pragma unroll
    for (int msk = 1; msk < 16; msk <<= 1){
      ps += __shfl_xor(ps, msk);
      pd += __shfl_xor(pd, msk);
    }
    if (tx == 0 && grow < M){ AS3[grow] = ps; AD3[grow] = pd; }
  }
}

// ---------------- layer-3 aggregation: max-only pass A, fused den+acc, log_softmax ----------------
__global__ __launch_bounds__(256) void agg3_kernel(
    const float* __restrict__ H3,
    const float* __restrict__ AS3, const float* __restrict__ AD3,
    const int* __restrict__ offsets, const int* __restrict__ csr_src,
    const float* __restrict__ bias, float* __restrict__ Out, int N)
{
  const int wave = threadIdx.x >> 6, lane = threadIdx.x & 63;
  const int d = blockIdx.x * 4 + wave;
  if (d >= N) return;
  const int beg = offsets[d], end = offsets[d + 1];
  const float adv = AD3[d];
  float m = -1e30f;
  for (int slot = beg + lane; slot < end; slot += 64){
    int s = csr_src[slot];
    m = fmaxf(m, lrelu(AS3[s] + adv));
  }
  #pragma unroll
  for (int msk = 1; msk < 64; msk <<= 1) m = fmaxf(m, __shfl_xor(m, msk));

  const int c = lane & 15;
  float acc = 0.f, den = 0.f;
  for (int slot = beg + (lane >> 4); slot < end; slot += 4){
    int s = csr_src[slot];
    float e = __expf(lrelu(AS3[s] + adv) - m);
    den += e;
    acc += e * H3[(size_t)s * 16 + c];
  }
  acc += __shfl_xor(acc, 16);
  acc += __shfl_xor(acc, 32);
  den += __shfl_xor(den, 16);
  den += __shfl_xor(den, 32);
  float v = acc / fmaxf(den, 1e-16f) + bias[c];
  float mm = v;
  #pragma unroll
  for (int msk = 1; msk < 16; msk <<= 1) mm = fmaxf(mm, __shfl_xor(mm, msk));
  float se = __expf(v - mm);
  #pragma unroll
  for (int msk = 1; msk < 16; msk <<= 1) se += __shfl_xor(se, msk);
  float r = v - mm - __logf(se);
  if (lane < 16) Out[(size_t)d * 16 + lane] = r;
}

extern "C" void kernel_launch(void* const* d_in, const int* in_sizes, int n_in,
                              void* d_out, int out_size, void* d_ws, size_t ws_size,
                              hipStream_t stream)
{
  const float* x   = (const float*)d_in[0];
  const int*   ei  = (const int*)d_in[1];
  const float* W1  = (const float*)d_in[2];
  const float* as1 = (const float*)d_in[3];
  const float* ad1 = (const float*)d_in[4];
  const float* b1  = (const float*)d_in[5];
  const float* W2  = (const float*)d_in[6];
  const float* as2 = (const float*)d_in[7];
  const float* ad2 = (const float*)d_in[8];
  const float* b2  = (const float*)d_in[9];
  const float* W3  = (const float*)d_in[10];
  const float* as3 = (const float*)d_in[11];
  const float* ad3 = (const float*)d_in[12];
  const float* b3  = (const float*)d_in[13];

  const int N    = in_sizes[0] / 256;
  const int E    = in_sizes[1] / 2;
  const int Et   = E + N;
  const int Mpad = (N + 127) & ~127;
  const int nb   = (N + 255) / 256;
  const int* src = ei;
  const int* dst = ei + E;

  char* base = (char*)d_ws;
  size_t off = 0;
  auto take = [&](size_t bytes) -> char* {
    char* p = base + off;
    off = (off + bytes + 255) & ~(size_t)255;
    return p;
  };
  _Float16* x16  = (_Float16*)take((size_t)Mpad * 256 * 2);
  _Float16* O16  = (_Float16*)take((size_t)Mpad * 512 * 2);
  unsigned char* H8 = (unsigned char*)take((size_t)Mpad * 512);
  float* SC   = (float*)take((size_t)Mpad * 8 * 4);
  _Float16* W1T  = (_Float16*)take((size_t)512 * 256 * 2);
  _Float16* W2T  = (_Float16*)take((size_t)512 * 512 * 2);
  float* AS   = (float*)take((size_t)N * 8 * 4);
  float* AD   = (float*)take((size_t)N * 8 * 4);
  float* H3   = (float*)take((size_t)N * 16 * 4);
  float* AS3  = (float*)take((size_t)N * 4);
  float* AD3  = (float*)take((size_t)N * 4);
  int* counts  = (int*)take((size_t)2 * N * 4);
  int* cursor  = counts + N;
  int* offsets = (int*)take((size_t)(N + 1) * 4);
  int* bsum    = (int*)take((size_t)(nb + 1) * 4);
  int* csr     = (int*)take((size_t)Et * 4);
  if (off > ws_size) return;

  hipMemsetAsync(counts, 0, (size_t)2 * N * 4, stream);
  const int tb = 256;
  const int cvtb = Mpad / 8;
  const int cntb = (Et + tb - 1) / tb;
  prep_kernel<<<cvtb + 384 + cntb, tb, 0, stream>>>(
      x, x16, cvtb, N * 256, Mpad * 256, W1, W1T, W2, W2T, dst, E, N, counts);
  block_sum_kernel<<<nb, 256, 0, stream>>>(counts, N, bsum);
  scan_bsum_kernel<<<1, 256, 0, stream>>>(bsum, nb, offsets, N);
  scan_within_kernel<<<nb, 256, 0, stream>>>(counts, bsum, offsets, N);
  fill_kernel<<<(Et + tb - 1) / tb, tb, 0, stream>>>(src, dst, E, N, offsets, cursor, csr);

  const int gM = Mpad / 64;
  // layer 1
  gemm_f16_mfma_q<<<dim3(gM, 4), 256, 0, stream>>>(x16, W1T, H8, SC, as1, ad1, AS, AD, N, 512, 256);
  agg_f8<<<(N + 1) / 2, 128, 0, stream>>>(H8, SC, AS, AD, offsets, csr, b1, O16, N);
  // layer 2
  gemm_f16_mfma_q<<<dim3(gM, 4), 256, 0, stream>>>(O16, W2T, H8, SC, as2, ad2, AS, AD, N, 512, 512);
  agg_f8<<<(N + 1) / 2, 128, 0, stream>>>(H8, SC, AS, AD, offsets, csr, b2, O16, N);
  // layer 3
  gemm_n16_f16<<<(N + 63) / 64, 256, 0, stream>>>(O16, W3, H3, as3, ad3, AS3, AD3, N, 512);
  agg3_kernel<<<(N + 3) / 4, 256, 0, stream>>>(H3, AS3, AD3, offsets, csr, b3, (float*)d_out, N);
}

// Round 9
// 200.265 us; speedup vs baseline: 1.3689x; 1.0857x over previous
//
#include <hip/hip_runtime.h>
#include <hip/hip_fp8.h>

#define NEG_SLOPE 0.2f

typedef _Float16 f16x8 __attribute__((ext_vector_type(8)));
typedef float f32x4 __attribute__((ext_vector_type(4)));
typedef float f32x2 __attribute__((ext_vector_type(2)));

#if defined(__has_builtin)
#if __has_builtin(__builtin_amdgcn_cvt_pk_f32_fp8)
#define HAVE_PK_F32_FP8 1
#endif
#if __has_builtin(__builtin_amdgcn_cvt_pk_fp8_f32)
#define HAVE_PK_FP8_F32 1
#endif
#endif

__device__ __forceinline__ float lrelu(float x){ return x >= 0.0f ? x : NEG_SLOPE * x; }
__device__ __forceinline__ float elu1(float x){ return x > 0.0f ? x : __expf(x) - 1.0f; }

__device__ __forceinline__ void gload_lds16(const _Float16* g, _Float16* l){
  __builtin_amdgcn_global_load_lds(
      (const __attribute__((address_space(1))) unsigned int*)g,
      (__attribute__((address_space(3))) unsigned int*)l, 16, 0, 0);
}

__device__ __forceinline__ float f8_to_f32(unsigned char b){
  __hip_fp8_e4m3 t; t.__x = (__hip_fp8_storage_t)b; return (float)t;
}

// dword bytes k=0..3 -> f[k]; second dword -> f[4..7]
__device__ __forceinline__ void dq8(uint2 u, float* f){
#ifdef HAVE_PK_F32_FP8
  f32x2 a = __builtin_amdgcn_cvt_pk_f32_fp8(u.x, false);
  f32x2 b = __builtin_amdgcn_cvt_pk_f32_fp8(u.x, true);
  f32x2 c = __builtin_amdgcn_cvt_pk_f32_fp8(u.y, false);
  f32x2 d = __builtin_amdgcn_cvt_pk_f32_fp8(u.y, true);
  f[0]=a[0]; f[1]=a[1]; f[2]=b[0]; f[3]=b[1];
  f[4]=c[0]; f[5]=c[1]; f[6]=d[0]; f[7]=d[1];
#else
  const unsigned char* p = (const unsigned char*)&u;
  #pragma unroll
  for (int j = 0; j < 8; ++j) f[j] = f8_to_f32(p[j]);
#endif
}

__device__ __forceinline__ unsigned int pack4_fp8(float v0, float v1, float v2, float v3){
#ifdef HAVE_PK_FP8_F32
  int pk = __builtin_amdgcn_cvt_pk_fp8_f32(v0, v1, 0, false);
  pk = __builtin_amdgcn_cvt_pk_fp8_f32(v2, v3, pk, true);
  return (unsigned int)pk;
#else
  __hip_fp8_e4m3 q0(v0), q1(v1), q2(v2), q3(v3);
  return (unsigned int)q0.__x | ((unsigned int)q1.__x << 8) |
         ((unsigned int)q2.__x << 16) | ((unsigned int)q3.__x << 24);
#endif
}

union H8U { uint4 u; _Float16 h[8]; };
union P2U { _Float16 h[2]; unsigned int u; };

// ---------------- fused prep: convert x -> fp16, transpose W1/W2 -> fp16, count degrees ----------------
__global__ __launch_bounds__(256) void prep_kernel(
    const float* __restrict__ x, _Float16* __restrict__ x16, int cvtb, int valid, int total,
    const float* __restrict__ W1, _Float16* __restrict__ W1T,
    const float* __restrict__ W2, _Float16* __restrict__ W2T,
    const int* __restrict__ dstp, int E, int N, int* __restrict__ counts)
{
  __shared__ float tile[32][33];
  int b = blockIdx.x;
  const int tid = threadIdx.x;
  if (b < cvtb){
    int i = (b * 256 + tid) * 8;
    if (i < total){
      H8U o;
      if (i + 8 <= valid){
        float4 v0 = *(const float4*)(x + i);
        float4 v1 = *(const float4*)(x + i + 4);
        o.h[0] = (_Float16)v0.x; o.h[1] = (_Float16)v0.y; o.h[2] = (_Float16)v0.z; o.h[3] = (_Float16)v0.w;
        o.h[4] = (_Float16)v1.x; o.h[5] = (_Float16)v1.y; o.h[6] = (_Float16)v1.z; o.h[7] = (_Float16)v1.w;
      } else {
        #pragma unroll
        for (int j = 0; j < 8; ++j) o.h[j] = (i + j < valid) ? (_Float16)x[i + j] : (_Float16)0.0f;
      }
      *(uint4*)(x16 + i) = o.u;
    }
    return;
  }
  b -= cvtb;
  if (b < 128 + 256){
    const float* W; _Float16* WT; int K, Nn, bb;
    if (b < 128){ W = W1; WT = W1T; K = 256; Nn = 512; bb = b; }
    else        { W = W2; WT = W2T; K = 512; Nn = 512; bb = b - 128; }
    const int nbk = K / 32;
    const int k0 = (bb % nbk) * 32, n0 = (bb / nbk) * 32;
    const int tx = tid & 31, ty = tid >> 5;
    for (int i = ty; i < 32; i += 8)
      tile[i][tx] = W[(size_t)(k0 + i) * Nn + n0 + tx];
    __syncthreads();
    for (int i = ty; i < 32; i += 8)
      WT[(size_t)(n0 + i) * K + k0 + tx] = (_Float16)tile[tx][i];
    return;
  }
  b -= 384;
  {
    int i = b * 256 + tid;
    if (i < E + N){
      int d = (i < E) ? dstp[i] : (i - E);
      atomicAdd(&counts[d], 1);
    }
  }
}

// ---------------- CSR scan / fill ----------------
__global__ __launch_bounds__(256) void block_sum_kernel(const int* __restrict__ counts, int N, int* __restrict__ bsum){
  __shared__ int ws[4];
  const int lane = threadIdx.x & 63, wave = threadIdx.x >> 6;
  int i = blockIdx.x * 256 + threadIdx.x;
  int v = (i < N) ? counts[i] : 0;
  #pragma unroll
  for (int msk = 1; msk < 64; msk <<= 1) v += __shfl_xor(v, msk);
  if (lane == 0) ws[wave] = v;
  __syncthreads();
  if (threadIdx.x == 0) bsum[blockIdx.x] = ws[0] + ws[1] + ws[2] + ws[3];
}

__global__ __launch_bounds__(256) void scan_bsum_kernel(int* __restrict__ bsum, int nb, int* __restrict__ offsets, int N){
  __shared__ int tmp[256];
  const int t = threadIdx.x;
  int v = (t < nb) ? bsum[t] : 0;
  tmp[t] = v;
  __syncthreads();
  #pragma unroll
  for (int ofs = 1; ofs < 256; ofs <<= 1){
    int add = (t >= ofs) ? tmp[t - ofs] : 0;
    __syncthreads();
    tmp[t] += add;
    __syncthreads();
  }
  if (t < nb) bsum[t] = tmp[t] - v;
  if (t == nb - 1) offsets[N] = tmp[t];
}

__global__ __launch_bounds__(256) void scan_within_kernel(const int* __restrict__ counts, const int* __restrict__ bsum,
                                                          int* __restrict__ offsets, int N){
  __shared__ int wsum[4];
  const int lane = threadIdx.x & 63, wave = threadIdx.x >> 6;
  int i = blockIdx.x * 256 + threadIdx.x;
  int v = (i < N) ? counts[i] : 0;
  int sc = v;
  #pragma unroll
  for (int ofs = 1; ofs < 64; ofs <<= 1){
    int t = __shfl_up(sc, ofs);
    if (lane >= ofs) sc += t;
  }
  if (lane == 63) wsum[wave] = sc;
  __syncthreads();
  int woff = 0;
  #pragma unroll
  for (int w = 0; w < 4; ++w) if (w < wave) woff += wsum[w];
  if (i < N) offsets[i] = bsum[blockIdx.x] + woff + sc - v;
}

__global__ void fill_kernel(const int* __restrict__ src, const int* __restrict__ dst, int E, int N,
                            const int* __restrict__ offsets, int* __restrict__ cursor, int* __restrict__ csr_src){
  int i = blockIdx.x * blockDim.x + threadIdx.x;
  if (i < E + N){
    int s, d;
    if (i < E){ s = src[i]; d = dst[i]; } else { s = i - E; d = i - E; }
    int pos = atomicAdd(&cursor[d], 1);
    csr_src[offsets[d] + pos] = s;
  }
}

// ---------------- fp16 MFMA GEMM (64x128 tile, XOR-swizzled LDS) + fused alpha + fp8 quantize ----------------
// LDS chunk (r, c) holds global chunk (c ^ (r&7)) of row r  [chunk = 16B = 8 f16]
// H8 row layout: per (row, head) 16 dwords; dword q holds cols {16k+q, k=0..3}.
// ASC[row*8+head] = {alpha_src_score, fp8_scale}
__global__ __launch_bounds__(256) void gemm_f16_mfma_q(
    const _Float16* __restrict__ A, const _Float16* __restrict__ BT,
    unsigned char* __restrict__ H8, float2* __restrict__ ASC,
    const float* __restrict__ a_src, const float* __restrict__ a_dst,
    float* __restrict__ AD,
    int M, int Nn, int K)
{
  __shared__ _Float16 As[64 * 64];    // 8 KB
  __shared__ _Float16 Bs[128 * 64];   // 16 KB
  const int tid = threadIdx.x;
  const int lane = tid & 63;
  const int wave = tid >> 6;
  const int wr = wave >> 1, wc = wave & 1;   // wave: 32 rows x 64 cols
  const int row0 = blockIdx.x * 64;
  const int col0 = blockIdx.y * 128;
  const int r15 = lane & 15;
  const int kgrp = lane >> 4;
  const int head = 2 * blockIdx.y + wc;
  const int sw = r15 & 7;                    // read-side XOR swizzle

  f32x4 acc[2][4];
  #pragma unroll
  for (int m = 0; m < 2; ++m)
    #pragma unroll
    for (int n = 0; n < 4; ++n)
      acc[m][n] = (f32x4){0.f, 0.f, 0.f, 0.f};

  for (int k0 = 0; k0 < K; k0 += 64){
    #pragma unroll
    for (int it = 0; it < 2; ++it){
      int ci = it * 256 + tid;
      int r = ci >> 3, ch = (ci & 7) ^ (r & 7);
      gload_lds16(A + (size_t)(row0 + r) * K + k0 + ch * 8, &As[ci * 8]);
    }
    #pragma unroll
    for (int it = 0; it < 4; ++it){
      int ci = it * 256 + tid;
      int r = ci >> 3, ch = (ci & 7) ^ (r & 7);
      gload_lds16(BT + (size_t)(col0 + r) * K + k0 + ch * 8, &Bs[ci * 8]);
    }
    __syncthreads();
    #pragma unroll
    for (int kk = 0; kk < 2; ++kk){
      f16x8 av[2], bv[4];
      #pragma unroll
      for (int q = 0; q < 2; ++q){
        int rr = wr * 32 + q * 16 + r15;
        av[q] = *(const f16x8*)&As[rr * 64 + (((kgrp + kk * 4) ^ sw) * 8)];
      }
      #pragma unroll
      for (int q = 0; q < 4; ++q){
        int rr = wc * 64 + q * 16 + r15;
        bv[q] = *(const f16x8*)&Bs[rr * 64 + (((kgrp + kk * 4) ^ sw) * 8)];
      }
      #pragma unroll
      for (int m = 0; m < 2; ++m)
        #pragma unroll
        for (int n = 0; n < 4; ++n)
          acc[m][n] = __builtin_amdgcn_mfma_f32_16x16x32_f16(av[m], bv[n], acc[m][n], 0, 0, 0);
    }
    __syncthreads();
  }

  // alpha epilogue: wave owns `head` over its 32 rows
  float asv[4], adv[4];
  #pragma unroll
  for (int n = 0; n < 4; ++n){
    asv[n] = a_src[head * 64 + n * 16 + r15];
    adv[n] = a_dst[head * 64 + n * 16 + r15];
  }
  // fp8 quantize + alpha, fused per (m,j) row
  #pragma unroll
  for (int m = 0; m < 2; ++m){
    #pragma unroll
    for (int j = 0; j < 4; ++j){
      float ps = 0.f, pd = 0.f, a = 0.f;
      #pragma unroll
      for (int n = 0; n < 4; ++n){
        float c = acc[m][n][j];
        ps += c * asv[n];
        pd += c * adv[n];
        a = fmaxf(a, fabsf(c));
      }
      #pragma unroll
      for (int msk = 1; msk < 16; msk <<= 1){
        ps += __shfl_xor(ps, msk);
        pd += __shfl_xor(pd, msk);
        a = fmaxf(a, __shfl_xor(a, msk));
      }
      float inv = (a > 1e-30f) ? (448.0f / a) : 0.0f;
      int row = row0 + wr * 32 + m * 16 + kgrp * 4 + j;
      unsigned int pk = pack4_fp8(acc[m][0][j] * inv, acc[m][1][j] * inv,
                                  acc[m][2][j] * inv, acc[m][3][j] * inv);
      *(unsigned int*)(H8 + (size_t)row * 512 + head * 64 + r15 * 4) = pk;
      if (r15 == 0 && row < M){
        ASC[(size_t)row * 8 + head] = make_float2(ps, a * (1.0f / 448.0f));
        AD[(size_t)row * 8 + head] = pd;
      }
    }
  }
}

// ---------------- GAT aggregation over fp8 H: single pass (no max), 4-deep gather, fp32 accumulate ----------------
// lane = hA*8 + l3 reads dwords (2l3, 2l3+1) of head hA: f[k] -> col 16k+2l3, f[k+4] -> col 16k+2l3+1
__global__ __launch_bounds__(128) void agg_f8(
    const unsigned char* __restrict__ H8, const float2* __restrict__ ASC,
    const float* __restrict__ AD,
    const int* __restrict__ offsets, const int* __restrict__ csr_src,
    const float* __restrict__ bias, _Float16* __restrict__ O16, int N)
{
  const int wave = threadIdx.x >> 6, lane = threadIdx.x & 63;
  const int d = blockIdx.x * 2 + wave;
  if (d >= N) return;
  const int beg = offsets[d], end = offsets[d + 1];
  const int hA = lane >> 3;    // head owning this lane's output channels
  const int l3 = lane & 7;
  const float aH = AD[(size_t)d * 8 + hA];

  float acc[8];
  #pragma unroll
  for (int j = 0; j < 8; ++j) acc[j] = 0.f;
  float den = 0.f;
  const unsigned char* Hb = H8 + lane * 8;
  int slot = beg;
  for (; slot + 4 <= end; slot += 4){
    int s[4]; float2 pc[4]; uint2 u[4];
    #pragma unroll
    for (int q = 0; q < 4; ++q) s[q] = csr_src[slot + q];
    #pragma unroll
    for (int q = 0; q < 4; ++q) pc[q] = ASC[(size_t)s[q] * 8 + hA];
    #pragma unroll
    for (int q = 0; q < 4; ++q) u[q] = *(const uint2*)(Hb + (size_t)s[q] * 512);
    #pragma unroll
    for (int q = 0; q < 4; ++q){
      float e = __expf(fminf(lrelu(pc[q].x + aH), 60.0f));
      den += e;
      float w = e * pc[q].y;
      float f[8];
      dq8(u[q], f);
      #pragma unroll
      for (int j = 0; j < 8; ++j) acc[j] += w * f[j];
    }
  }
  for (; slot < end; ++slot){
    int s0 = csr_src[slot];
    float2 pc = ASC[(size_t)s0 * 8 + hA];
    uint2 u0 = *(const uint2*)(Hb + (size_t)s0 * 512);
    float e = __expf(fminf(lrelu(pc.x + aH), 60.0f));
    den += e;
    float w = e * pc.y;
    float f[8];
    dq8(u0, f);
    #pragma unroll
    for (int j = 0; j < 8; ++j) acc[j] += w * f[j];
  }

  const float di = 1.0f / fmaxf(den, 1e-16f);
  _Float16* Ob = O16 + (size_t)d * 512 + hA * 64 + 2 * l3;
  const float* Bb = bias + hA * 64 + 2 * l3;
  #pragma unroll
  for (int j = 0; j < 4; ++j){
    float2 bv = *(const float2*)(Bb + j * 16);
    P2U P;
    P.h[0] = (_Float16)elu1(acc[j] * di + bv.x);
    P.h[1] = (_Float16)elu1(acc[j + 4] * di + bv.y);
    *(unsigned int*)(Ob + j * 16) = P.u;
  }
}

// ---------------- narrow GEMM + fused alpha3 ----------------
__global__ __launch_bounds__(256) void gemm_n16_f16(const _Float16* __restrict__ X, const float* __restrict__ W,
                                                    float* __restrict__ Y,
                                                    const float* __restrict__ a3s, const float* __restrict__ a3d,
                                                    float* __restrict__ AS3, float* __restrict__ AD3,
                                                    int M, int K){
  __shared__ float Ws[512 * 16];
  __shared__ float Xs[64][68];
  const int tid = threadIdx.x;
  for (int i = tid; i < K * 16; i += 256) Ws[i] = W[i];
  const int tx = tid & 15;
  const int ty = tid >> 4;
  const int row0 = blockIdx.x * 64;
  float acc[4] = {0.f, 0.f, 0.f, 0.f};
  for (int k0 = 0; k0 < K; k0 += 64){
    __syncthreads();
    #pragma unroll
    for (int it = 0; it < 2; ++it){
      int idx = it * 2048 + tid * 8;
      int r = idx >> 6, c = idx & 63;
      H8U U; U.u = *(const uint4*)(X + (size_t)(row0 + r) * K + k0 + c);
      float4 f0 = make_float4((float)U.h[0], (float)U.h[1], (float)U.h[2], (float)U.h[3]);
      float4 f1 = make_float4((float)U.h[4], (float)U.h[5], (float)U.h[6], (float)U.h[7]);
      *(float4*)&Xs[r][c] = f0;
      *(float4*)&Xs[r][c + 4] = f1;
    }
    __syncthreads();
    #pragma unroll
    for (int kk = 0; kk < 64; ++kk){
      float w = Ws[(k0 + kk) * 16 + tx];
      #pragma unroll
      for (int i = 0; i < 4; ++i) acc[i] += Xs[ty * 4 + i][kk] * w;
    }
  }
  const float sc = a3s[tx], dc = a3d[tx];
  #pragma unroll
  for (int i = 0; i < 4; ++i){
    int grow = row0 + ty * 4 + i;
    if (grow < M) Y[(size_t)grow * 16 + tx] = acc[i];
    float ps = acc[i] * sc, pd = acc[i] * dc;
    #pragma unroll
    for (int msk = 1; msk < 16; msk <<= 1){
      ps += __shfl_xor(ps, msk);
      pd += __shfl_xor(pd, msk);
    }
    if (tx == 0 && grow < M){ AS3[grow] = ps; AD3[grow] = pd; }
  }
}

// ---------------- layer-3 aggregation: single pass (no max), fused den+acc, log_softmax ----------------
__global__ __launch_bounds__(256) void agg3_kernel(
    const float* __restrict__ H3,
    const float* __restrict__ AS3, const float* __restrict__ AD3,
    const int* __restrict__ offsets, const int* __restrict__ csr_src,
    const float* __restrict__ bias, float* __restrict__ Out, int N)
{
  const int wave = threadIdx.x >> 6, lane = threadIdx.x & 63;
  const int d = blockIdx.x * 4 + wave;
  if (d >= N) return;
  const int beg = offsets[d], end = offsets[d + 1];
  const float adv = AD3[d];
  const int c = lane & 15;
  float acc = 0.f, den = 0.f;
  for (int slot = beg + (lane >> 4); slot < end; slot += 4){
    int s = csr_src[slot];
    float e = __expf(fminf(lrelu(AS3[s] + adv), 60.0f));
    den += e;
    acc += e * H3[(size_t)s * 16 + c];
  }
  acc += __shfl_xor(acc, 16);
  acc += __shfl_xor(acc, 32);
  den += __shfl_xor(den, 16);
  den += __shfl_xor(den, 32);
  float v = acc / fmaxf(den, 1e-16f) + bias[c];
  float mm = v;
  #pragma unroll
  for (int msk = 1; msk < 16; msk <<= 1) mm = fmaxf(mm, __shfl_xor(mm, msk));
  float se = __expf(v - mm);
  #pragma unroll
  for (int msk = 1; msk < 16; msk <<= 1) se += __shfl_xor(se, msk);
  float r = v - mm - __logf(se);
  if (lane < 16) Out[(size_t)d * 16 + lane] = r;
}

extern "C" void kernel_launch(void* const* d_in, const int* in_sizes, int n_in,
                              void* d_out, int out_size, void* d_ws, size_t ws_size,
                              hipStream_t stream)
{
  const float* x   = (const float*)d_in[0];
  const int*   ei  = (const int*)d_in[1];
  const float* W1  = (const float*)d_in[2];
  const float* as1 = (const float*)d_in[3];
  const float* ad1 = (const float*)d_in[4];
  const float* b1  = (const float*)d_in[5];
  const float* W2  = (const float*)d_in[6];
  const float* as2 = (const float*)d_in[7];
  const float* ad2 = (const float*)d_in[8];
  const float* b2  = (const float*)d_in[9];
  const float* W3  = (const float*)d_in[10];
  const float* as3 = (const float*)d_in[11];
  const float* ad3 = (const float*)d_in[12];
  const float* b3  = (const float*)d_in[13];

  const int N    = in_sizes[0] / 256;
  const int E    = in_sizes[1] / 2;
  const int Et   = E + N;
  const int Mpad = (N + 127) & ~127;
  const int nb   = (N + 255) / 256;
  const int* src = ei;
  const int* dst = ei + E;

  char* base = (char*)d_ws;
  size_t off = 0;
  auto take = [&](size_t bytes) -> char* {
    char* p = base + off;
    off = (off + bytes + 255) & ~(size_t)255;
    return p;
  };
  _Float16* x16  = (_Float16*)take((size_t)Mpad * 256 * 2);
  _Float16* O16  = (_Float16*)take((size_t)Mpad * 512 * 2);
  unsigned char* H8 = (unsigned char*)take((size_t)Mpad * 512);
  float2* ASC = (float2*)take((size_t)Mpad * 8 * 8);
  _Float16* W1T  = (_Float16*)take((size_t)512 * 256 * 2);
  _Float16* W2T  = (_Float16*)take((size_t)512 * 512 * 2);
  float* AD   = (float*)take((size_t)Mpad * 8 * 4);
  float* H3   = (float*)take((size_t)N * 16 * 4);
  float* AS3  = (float*)take((size_t)N * 4);
  float* AD3  = (float*)take((size_t)N * 4);
  int* counts  = (int*)take((size_t)2 * N * 4);
  int* cursor  = counts + N;
  int* offsets = (int*)take((size_t)(N + 1) * 4);
  int* bsum    = (int*)take((size_t)(nb + 1) * 4);
  int* csr     = (int*)take((size_t)Et * 4);
  if (off > ws_size) return;

  hipMemsetAsync(counts, 0, (size_t)2 * N * 4, stream);
  const int tb = 256;
  const int cvtb = Mpad / 8;
  const int cntb = (Et + tb - 1) / tb;
  prep_kernel<<<cvtb + 384 + cntb, tb, 0, stream>>>(
      x, x16, cvtb, N * 256, Mpad * 256, W1, W1T, W2, W2T, dst, E, N, counts);
  block_sum_kernel<<<nb, 256, 0, stream>>>(counts, N, bsum);
  scan_bsum_kernel<<<1, 256, 0, stream>>>(bsum, nb, offsets, N);
  scan_within_kernel<<<nb, 256, 0, stream>>>(counts, bsum, offsets, N);
  fill_kernel<<<(Et + tb - 1) / tb, tb, 0, stream>>>(src, dst, E, N, offsets, cursor, csr);

  const int gM = Mpad / 64;
  // layer 1
  gemm_f16_mfma_q<<<dim3(gM, 4), 256, 0, stream>>>(x16, W1T, H8, ASC, as1, ad1, AD, N, 512, 256);
  agg_f8<<<(N + 1) / 2, 128, 0, stream>>>(H8, ASC, AD, offsets, csr, b1, O16, N);
  // layer 2
  gemm_f16_mfma_q<<<dim3(gM, 4), 256, 0, stream>>>(O16, W2T, H8, ASC, as2, ad2, AD, N, 512, 512);
  agg_f8<<<(N + 1) / 2, 128, 0, stream>>>(H8, ASC, AD, offsets, csr, b2, O16, N);
  // layer 3
  gemm_n16_f16<<<(N + 63) / 64, 256, 0, stream>>>(O16, W3, H3, as3, ad3, AS3, AD3, N, 512);
  agg3_kernel<<<(N + 3) / 4, 256, 0, stream>>>(H3, AS3, AD3, offsets, csr, b3, (float*)d_out, N);
}